// Round 11
// baseline (63084.027 us; speedup 1.0000x reference)
//
#include <hip/hip_runtime.h>
#include <math.h>

#define BB 128
#define TT 256
#define HH 512
#define VV 32
#define MLEN 128
#define NBLK 128          // one batch column per block

typedef long long ll;

// ---- workspace layout (float offsets) ----
#define TP_OFF   ((ll)BB * TT * HH)                 // emb-projection T [3*HH][VV]
#define W0T_OFF  (TP_OFF + (ll)3 * HH * VV)         // enc L0: f4(er,ez,en,0)[d][j]
#define W1A_OFF  (W0T_OFF + (ll)HH * HH * 4)        // enc L1: f4(f1r,f1z,f1n,g1r)[d][j]
#define W1B_OFF  (W1A_OFF + (ll)HH * HH * 4)        // enc L1: f2(g1z,g1n)[d][j]
#define D0A_OFF  (W1B_OFF + (ll)HH * HH * 2)        // dec L0: f4(c0r,c0z,c0n,u0r)[d][j]
#define D0B_OFF  (D0A_OFF + (ll)HH * HH * 4)        // dec L0: f2(u0z,u0n)[d][j]
#define D1A_OFF  (D0B_OFF + (ll)HH * HH * 2)        // dec L1: f4(c1r,c1z,c1n,u1r)[d][j]
#define D1B_OFF  (D1A_OFF + (ll)HH * HH * 4)        // dec L1: f2(u1z,u1n)[d][j]
#define QTT_OFF  (D1B_OFF + (ll)HH * HH * 2)        // qW^T: f4(4 d's)[d4][j]
#define WS_NEED_BYTES ((QTT_OFF + (ll)HH * HH) * 4) // ~91.4 MB

struct P {
    const float *x, *emb;
    const float *eWih0, *eWhh0, *ebih0, *ebhh0;
    const float *eWih1, *eWhh1, *ebih1, *ebhh1;
    const float *dWih0, *dWhh0, *dbih0, *dbhh0;
    const float *dWih1, *dWhh1, *dbih1, *dbhh1;
    const float *qW, *qb, *outW, *outb;
    float *ws;
    float *vecO, *hidO, *attnO;
};

__device__ __forceinline__ float sigf(float v) { return 1.0f / (1.0f + __expf(-v)); }
__device__ __forceinline__ float dot4(float4 a, float4 b, float acc) {
    return fmaf(a.x, b.x, fmaf(a.y, b.y, fmaf(a.z, b.z, fmaf(a.w, b.w, acc))));
}

#define G6(WA, WB, iv, hv)                                                     \
    do {                                                                       \
        pr = fmaf((WA).x, (iv), pr); pz = fmaf((WA).y, (iv), pz);              \
        pn = fmaf((WA).z, (iv), pn); hr = fmaf((WA).w, (hv), hr);              \
        hz = fmaf((WB).x, (hv), hz); hn = fmaf((WB).y, (hv), hn);              \
    } while (0)

// 6-gate packed GEMV slice for output j: rolling 4-chunk register pipeline
// (~16 f4 + 16 f2 loads in flight; static buffer indices via full unroll).
__device__ __forceinline__ void gemv6_pk(const float4* wA, const float2* wB,
                                         const float4* iv, const float4* hv, int j,
                                         float& pr_, float& pz_, float& pn_,
                                         float& hr_, float& hz_, float& hn_) {
    float pr = 0, pz = 0, pn = 0, hr = 0, hz = 0, hn = 0;
    float4 A[4][4];
    float2 B[4][4];
#pragma unroll
    for (int c = 0; c < 4; ++c)
#pragma unroll
        for (int u = 0; u < 4; ++u) {
            A[c][u] = wA[(c * 4 + u) * HH + j];
            B[c][u] = wB[(c * 4 + u) * HH + j];
        }
    int d4 = 0;
    for (; d4 < HH / 4 - 4; d4 += 4) {
#pragma unroll
        for (int c = 0; c < 4; ++c) {
            const int dd = d4 + c;
            float4 a4 = iv[dd], h4 = hv[dd];
            float av[4] = {a4.x, a4.y, a4.z, a4.w};
            float cv[4] = {h4.x, h4.y, h4.z, h4.w};
#pragma unroll
            for (int u = 0; u < 4; ++u) G6(A[c][u], B[c][u], av[u], cv[u]);
#pragma unroll
            for (int u = 0; u < 4; ++u) {
                A[c][u] = wA[((dd + 4) * 4 + u) * HH + j];
                B[c][u] = wB[((dd + 4) * 4 + u) * HH + j];
            }
        }
    }
#pragma unroll
    for (int c = 0; c < 4; ++c) {
        const int dd = d4 + c;
        float4 a4 = iv[dd], h4 = hv[dd];
        float av[4] = {a4.x, a4.y, a4.z, a4.w};
        float cv[4] = {h4.x, h4.y, h4.z, h4.w};
#pragma unroll
        for (int u = 0; u < 4; ++u) G6(A[c][u], B[c][u], av[u], cv[u]);
    }
    pr_ = pr; pz_ = pz; pn_ = pn; hr_ = hr; hz_ = hz; hn_ = hn;
}

// 3-gate packed GEMV (enc L0): rolling 4-chunk pipeline, f4 only.
__device__ __forceinline__ void gemv3_pk(const float4* w0, const float4* hv, int j,
                                         float& ar_, float& az_, float& an_) {
    float ar = 0, az = 0, an = 0;
    float4 A[4][4];
#pragma unroll
    for (int c = 0; c < 4; ++c)
#pragma unroll
        for (int u = 0; u < 4; ++u) A[c][u] = w0[(c * 4 + u) * HH + j];
    int d4 = 0;
    for (; d4 < HH / 4 - 4; d4 += 4) {
#pragma unroll
        for (int c = 0; c < 4; ++c) {
            const int dd = d4 + c;
            float4 h4 = hv[dd];
            float cv[4] = {h4.x, h4.y, h4.z, h4.w};
#pragma unroll
            for (int u = 0; u < 4; ++u) {
                ar = fmaf(A[c][u].x, cv[u], ar);
                az = fmaf(A[c][u].y, cv[u], az);
                an = fmaf(A[c][u].z, cv[u], an);
            }
#pragma unroll
            for (int u = 0; u < 4; ++u) A[c][u] = w0[((dd + 4) * 4 + u) * HH + j];
        }
    }
#pragma unroll
    for (int c = 0; c < 4; ++c) {
        const int dd = d4 + c;
        float4 h4 = hv[dd];
        float cv[4] = {h4.x, h4.y, h4.z, h4.w};
#pragma unroll
        for (int u = 0; u < 4; ++u) {
            ar = fmaf(A[c][u].x, cv[u], ar);
            az = fmaf(A[c][u].y, cv[u], az);
            an = fmaf(A[c][u].z, cv[u], an);
        }
    }
    ar_ = ar; az_ = az; an_ = an;
}

// query GEMV: rolling 8-slot pipeline.
__device__ __forceinline__ float gemvq_pk(const float4* qt, const float4* hv, int j) {
    float a = 0;
    float4 A[8];
#pragma unroll
    for (int c = 0; c < 8; ++c) A[c] = qt[c * HH + j];
    int d4 = 0;
    for (; d4 < HH / 4 - 8; d4 += 8) {
#pragma unroll
        for (int c = 0; c < 8; ++c) {
            a = dot4(A[c], hv[d4 + c], a);
            A[c] = qt[(d4 + 8 + c) * HH + j];
        }
    }
#pragma unroll
    for (int c = 0; c < 8; ++c) a = dot4(A[c], hv[d4 + c], a);
    return a;
}

// ---- prep: gate-packed weight transposes + emb-projection table ----
__global__ void kprep(P p) {
    const ll nt = (ll)gridDim.x * blockDim.x;
    const ll id0 = (ll)blockIdx.x * blockDim.x + threadIdx.x;
    float* ws = p.ws;
    for (ll i = id0; i < (ll)HH * HH; i += nt) {
        int d = (int)(i >> 9), j = (int)(i & 511);
        ((float4*)(ws + W0T_OFF))[i] = make_float4(
            p.eWhh0[(ll)j * HH + d], p.eWhh0[(ll)(HH + j) * HH + d],
            p.eWhh0[(ll)(2 * HH + j) * HH + d], 0.0f);
        ((float4*)(ws + W1A_OFF))[i] = make_float4(
            p.eWih1[(ll)j * HH + d], p.eWih1[(ll)(HH + j) * HH + d],
            p.eWih1[(ll)(2 * HH + j) * HH + d], p.eWhh1[(ll)j * HH + d]);
        ((float2*)(ws + W1B_OFF))[i] = make_float2(
            p.eWhh1[(ll)(HH + j) * HH + d], p.eWhh1[(ll)(2 * HH + j) * HH + d]);
        ((float4*)(ws + D0A_OFF))[i] = make_float4(
            p.dWih0[(ll)j * 1024 + 512 + d], p.dWih0[(ll)(HH + j) * 1024 + 512 + d],
            p.dWih0[(ll)(2 * HH + j) * 1024 + 512 + d], p.dWhh0[(ll)j * HH + d]);
        ((float2*)(ws + D0B_OFF))[i] = make_float2(
            p.dWhh0[(ll)(HH + j) * HH + d], p.dWhh0[(ll)(2 * HH + j) * HH + d]);
        ((float4*)(ws + D1A_OFF))[i] = make_float4(
            p.dWih1[(ll)j * HH + d], p.dWih1[(ll)(HH + j) * HH + d],
            p.dWih1[(ll)(2 * HH + j) * HH + d], p.dWhh1[(ll)j * HH + d]);
        ((float2*)(ws + D1B_OFF))[i] = make_float2(
            p.dWhh1[(ll)(HH + j) * HH + d], p.dWhh1[(ll)(2 * HH + j) * HH + d]);
    }
    for (ll i = id0; i < (ll)(HH / 4) * HH; i += nt) {
        int d4 = (int)(i >> 9), j = (int)(i & 511);
        const float* qr = p.qW + (ll)j * HH + d4 * 4;
        ((float4*)(ws + QTT_OFF))[i] = make_float4(qr[0], qr[1], qr[2], qr[3]);
    }
    for (ll u = id0; u < (ll)3 * HH * VV; u += nt) {
        int v = (int)(u & 31), gj = (int)(u >> 5);
        const float* wrow = p.dWih0 + (ll)gj * 1024;
        const float* erow = p.emb + (ll)v * HH;
        float acc = 0.0f;
#pragma unroll 8
        for (int d = 0; d < HH; ++d) acc = fmaf(wrow[d], erow[d], acc);
        (ws + TP_OFF)[u] = acc;
    }
}

template<int PK>
__global__ __launch_bounds__(512, 1) void kmain(P p) {
    __shared__ float h0m[2][HH];
    __shared__ float h1m[2][HH];
    __shared__ float qv[HH];
    __shared__ float cx[HH];
    __shared__ float sc[TT];
    __shared__ float xl[TT][2];
    __shared__ float embL[VV][HH];       // PK=0 only (DCE'd otherwise)
    __shared__ float red[16][VV];
    __shared__ float lgs[VV];
    __shared__ float mred[8];
    __shared__ int tkn;

    const int tid = threadIdx.x;
    const int blk = blockIdx.x;
    const int j = tid;
    float* ws = p.ws;
    float* encO = ws;                    // [128 b][256 t][512 j]
    float* Tp = ws + TP_OFF;

    // ================= INIT =================
    {
        int t = tid >> 1, c = tid & 1;
        xl[t][c] = p.x[((ll)blk * TT + t) * 2 + c];
    }
    h0m[0][j] = 0.0f;
    h1m[0][j] = 0.0f;
    if constexpr (!PK) {
        for (int i = tid; i < VV * HH; i += 512) embL[i >> 9][i & 511] = p.emb[i];
    }
    __syncthreads();
    if constexpr (!PK) {
        for (int g = 0; g < 3; ++g) {
            const float4* wrow = (const float4*)(p.dWih0 + (ll)(g * HH + j) * 1024);
            float acc[VV];
#pragma unroll
            for (int v = 0; v < VV; ++v) acc[v] = 0.0f;
            for (int d4 = 0; d4 < HH / 4; ++d4) {
                float4 w = wrow[d4];
#pragma unroll
                for (int v = 0; v < VV; ++v)
                    acc[v] = dot4(w, ((const float4*)embL[v])[d4], acc[v]);
            }
            for (int v = 0; v < VV; ++v) Tp[(ll)(g * HH + j) * VV + v] = acc[v];
        }
    }

    int cur = 0;

    const float wxr0 = p.eWih0[j * 2],            wxr1 = p.eWih0[j * 2 + 1];
    const float wxz0 = p.eWih0[(HH + j) * 2],     wxz1 = p.eWih0[(HH + j) * 2 + 1];
    const float wxn0 = p.eWih0[(2 * HH + j) * 2], wxn1 = p.eWih0[(2 * HH + j) * 2 + 1];
    const float bir = p.ebih0[j], biz = p.ebih0[HH + j], bin_ = p.ebih0[2 * HH + j];
    const float bhr = p.ebhh0[j], bhz = p.ebhh0[HH + j], bhn = p.ebhh0[2 * HH + j];
    const float cir = p.ebih1[j] + p.ebhh1[j];
    const float ciz = p.ebih1[HH + j] + p.ebhh1[HH + j];
    const float cin = p.ebih1[2 * HH + j];
    const float chn = p.ebhh1[2 * HH + j];

    // fallback row pointers (DCE'd when PK=1)
    const float4* er = (const float4*)(p.eWhh0 + (ll)j * HH);
    const float4* ez = (const float4*)(p.eWhh0 + (ll)(HH + j) * HH);
    const float4* en = (const float4*)(p.eWhh0 + (ll)(2 * HH + j) * HH);
    const float4* f1r = (const float4*)(p.eWih1 + (ll)j * HH);
    const float4* f1z = (const float4*)(p.eWih1 + (ll)(HH + j) * HH);
    const float4* f1n = (const float4*)(p.eWih1 + (ll)(2 * HH + j) * HH);
    const float4* g1r = (const float4*)(p.eWhh1 + (ll)j * HH);
    const float4* g1z = (const float4*)(p.eWhh1 + (ll)(HH + j) * HH);
    const float4* g1n = (const float4*)(p.eWhh1 + (ll)(2 * HH + j) * HH);

    // ================= ENCODER =================
    for (int t = 0; t < TT; ++t) {
        const int nxt = cur ^ 1;
        // layer 0
        {
            float ar = 0, az = 0, an = 0;
            const float4* ha = (const float4*)h0m[cur];
            if constexpr (PK) {
                gemv3_pk((const float4*)(ws + W0T_OFF), ha, j, ar, az, an);
            } else {
#pragma unroll 4
                for (int d4 = 0; d4 < HH / 4; ++d4) {
                    float4 a = ha[d4];
                    ar = dot4(er[d4], a, ar);
                    az = dot4(ez[d4], a, az);
                    an = dot4(en[d4], a, an);
                }
            }
            float x0 = xl[t][0], x1 = xl[t][1];
            float r = sigf(fmaf(wxr0, x0, fmaf(wxr1, x1, bir)) + ar + bhr);
            float z = sigf(fmaf(wxz0, x0, fmaf(wxz1, x1, biz)) + az + bhz);
            float n = tanhf(fmaf(wxn0, x0, fmaf(wxn1, x1, bin_)) + r * (an + bhn));
            h0m[nxt][j] = (1.0f - z) * n + z * h0m[cur][j];
        }
        __syncthreads();
        // layer 1 (input = new h0)
        {
            float pr, pz, pn, hr, hz, hn;
            if constexpr (PK) {
                gemv6_pk((const float4*)(ws + W1A_OFF), (const float2*)(ws + W1B_OFF),
                         (const float4*)h0m[nxt], (const float4*)h1m[cur], j,
                         pr, pz, pn, hr, hz, hn);
            } else {
                pr = pz = pn = hr = hz = hn = 0;
                const float4* ya = (const float4*)h0m[nxt];
                const float4* ha = (const float4*)h1m[cur];
#pragma unroll 2
                for (int d4 = 0; d4 < HH / 4; ++d4) {
                    float4 a = ya[d4], c = ha[d4];
                    pr = dot4(f1r[d4], a, pr); pz = dot4(f1z[d4], a, pz); pn = dot4(f1n[d4], a, pn);
                    hr = dot4(g1r[d4], c, hr); hz = dot4(g1z[d4], c, hz); hn = dot4(g1n[d4], c, hn);
                }
            }
            float r = sigf(pr + hr + cir);
            float z = sigf(pz + hz + ciz);
            float n = tanhf(pn + cin + r * (hn + chn));
            float hv = (1.0f - z) * n + z * h1m[cur][j];
            h1m[nxt][j] = hv;
            encO[((ll)blk * TT + t) * HH + j] = hv;
        }
        __syncthreads();
        cur ^= 1;
    }

    // ================= DEC-INIT =================
    const float qbj = p.qb[j];
    const float4* qw4 = (const float4*)(p.qW + (ll)j * HH);
    const float4* qt4 = (const float4*)(ws + QTT_OFF);
    {
        const float4* ha = (const float4*)h1m[cur];
        float a0;
        if constexpr (PK) {
            a0 = gemvq_pk(qt4, ha, j);
        } else {
            a0 = 0;
#pragma unroll 4
            for (int d4 = 0; d4 < HH / 4; ++d4) a0 = dot4(qw4[d4], ha[d4], a0);
        }
        qv[j] = a0 + qbj;
    }
    if (tid == 0) tkn = 0;
    __syncthreads();

    // fallback decoder row pointers (DCE'd when PK=1)
    const float4* c0r = (const float4*)(p.dWih0 + (ll)j * 1024 + 512);
    const float4* c0z = (const float4*)(p.dWih0 + (ll)(HH + j) * 1024 + 512);
    const float4* c0n = (const float4*)(p.dWih0 + (ll)(2 * HH + j) * 1024 + 512);
    const float4* u0r = (const float4*)(p.dWhh0 + (ll)j * HH);
    const float4* u0z = (const float4*)(p.dWhh0 + (ll)(HH + j) * HH);
    const float4* u0n = (const float4*)(p.dWhh0 + (ll)(2 * HH + j) * HH);
    const float4* c1r = (const float4*)(p.dWih1 + (ll)j * HH);
    const float4* c1z = (const float4*)(p.dWih1 + (ll)(HH + j) * HH);
    const float4* c1n = (const float4*)(p.dWih1 + (ll)(2 * HH + j) * HH);
    const float4* u1r = (const float4*)(p.dWhh1 + (ll)j * HH);
    const float4* u1z = (const float4*)(p.dWhh1 + (ll)(HH + j) * HH);
    const float4* u1n = (const float4*)(p.dWhh1 + (ll)(2 * HH + j) * HH);
    const float* Trj = Tp + (ll)j * VV;
    const float* Tzj = Tp + (ll)(HH + j) * VV;
    const float* Tnj = Tp + (ll)(2 * HH + j) * VV;
    const float d0r = p.dbih0[j] + p.dbhh0[j];
    const float d0z = p.dbih0[HH + j] + p.dbhh0[HH + j];
    const float d0in = p.dbih0[2 * HH + j];
    const float d0hn = p.dbhh0[2 * HH + j];
    const float d1r = p.dbih1[j] + p.dbhh1[j];
    const float d1z = p.dbih1[HH + j] + p.dbhh1[HH + j];
    const float d1in = p.dbih1[2 * HH + j];
    const float d1hn = p.dbhh1[2 * HH + j];

    // ================= DECODER =================
    for (int s = 0; s < MLEN; ++s) {
        const int nxt = cur ^ 1;
        // scores: pair (t = tid>>1, half = tid&1), shfl-combined
        {
            int t = tid >> 1, h = tid & 1;
            const float4* eRow = (const float4*)(encO + ((ll)blk * TT + t) * HH) + h * 64;
            const float4* q4 = (const float4*)qv + h * 64;
            float a = 0;
#pragma unroll 8
            for (int d4 = 0; d4 < 64; ++d4) a = dot4(q4[d4], eRow[d4], a);
            a += __shfl_down(a, 1);
            if (h == 0) sc[t] = a;
        }
        __syncthreads();
        if (tid < 64) {
            float m = fmaxf(fmaxf(sc[tid], sc[tid + 64]),
                            fmaxf(sc[tid + 128], sc[tid + 192]));
            for (int o = 32; o > 0; o >>= 1) m = fmaxf(m, __shfl_down(m, o));
            if (tid == 0) mred[0] = m;
        }
        __syncthreads();
        if (tid < 256) {
            float e = __expf(sc[tid] - mred[0]);
            sc[tid] = e;
            float ssum = e;
            for (int o = 32; o > 0; o >>= 1) ssum += __shfl_down(ssum, o);
            if ((tid & 63) == 0) mred[1 + (tid >> 6)] = ssum;
        }
        __syncthreads();
        if (tid < 256) {
            float l = mred[1] + mred[2] + mred[3] + mred[4];
            float w = sc[tid] / l;
            sc[tid] = w;
            p.attnO[((ll)blk * MLEN + s) * TT + tid] = w;
        }
        __syncthreads();
        // context
        {
            float c0 = 0;
            const float* e0 = encO + (ll)blk * TT * HH + j;
#pragma unroll 16
            for (int t2 = 0; t2 < TT; ++t2) c0 = fmaf(sc[t2], e0[(ll)t2 * HH], c0);
            cx[j] = c0;
        }
        __syncthreads();
        // G0
        {
            const int tk = tkn;
            float pr, pz, pn, hr, hz, hn;
            if constexpr (PK) {
                gemv6_pk((const float4*)(ws + D0A_OFF), (const float2*)(ws + D0B_OFF),
                         (const float4*)cx, (const float4*)h0m[cur], j,
                         pr, pz, pn, hr, hz, hn);
            } else {
                pr = pz = pn = hr = hz = hn = 0;
                const float4* xa = (const float4*)cx;
                const float4* ha = (const float4*)h0m[cur];
#pragma unroll 2
                for (int d4 = 0; d4 < HH / 4; ++d4) {
                    float4 a = xa[d4], c = ha[d4];
                    pr = dot4(c0r[d4], a, pr); pz = dot4(c0z[d4], a, pz); pn = dot4(c0n[d4], a, pn);
                    hr = dot4(u0r[d4], c, hr); hz = dot4(u0z[d4], c, hz); hn = dot4(u0n[d4], c, hn);
                }
            }
            float r = sigf(Trj[tk] + pr + hr + d0r);
            float z = sigf(Tzj[tk] + pz + hz + d0z);
            float n = tanhf(Tnj[tk] + pn + d0in + r * (hn + d0hn));
            h0m[nxt][j] = (1.0f - z) * n + z * h0m[cur][j];
        }
        __syncthreads();
        // G1
        {
            float pr, pz, pn, hr, hz, hn;
            if constexpr (PK) {
                gemv6_pk((const float4*)(ws + D1A_OFF), (const float2*)(ws + D1B_OFF),
                         (const float4*)h0m[nxt], (const float4*)h1m[cur], j,
                         pr, pz, pn, hr, hz, hn);
            } else {
                pr = pz = pn = hr = hz = hn = 0;
                const float4* ya = (const float4*)h0m[nxt];
                const float4* ha = (const float4*)h1m[cur];
#pragma unroll 2
                for (int d4 = 0; d4 < HH / 4; ++d4) {
                    float4 a = ya[d4], c = ha[d4];
                    pr = dot4(c1r[d4], a, pr); pz = dot4(c1z[d4], a, pz); pn = dot4(c1n[d4], a, pn);
                    hr = dot4(u1r[d4], c, hr); hz = dot4(u1z[d4], c, hz); hn = dot4(u1n[d4], c, hn);
                }
            }
            float r = sigf(pr + hr + d1r);
            float z = sigf(pz + hz + d1z);
            float n = tanhf(pn + d1in + r * (hn + d1hn));
            h1m[nxt][j] = (1.0f - z) * n + z * h1m[cur][j];
        }
        __syncthreads();
        // next-step query
        {
            const float4* ha = (const float4*)h1m[nxt];
            float a0;
            if constexpr (PK) {
                a0 = gemvq_pk(qt4, ha, j);
            } else {
                a0 = 0;
#pragma unroll 4
                for (int d4 = 0; d4 < HH / 4; ++d4) a0 = dot4(qw4[d4], ha[d4], a0);
            }
            qv[j] = a0 + qbj;
        }
        // logits: 16 chunks x 32 v
        {
            int v = tid & 31, ch = tid >> 5;
            const float4* wrow = (const float4*)(p.outW + (ll)v * HH + ch * 32);
            const float4* hrow = (const float4*)(&h1m[nxt][ch * 32]);
            float a = 0;
#pragma unroll
            for (int d4 = 0; d4 < 8; ++d4) a = dot4(wrow[d4], hrow[d4], a);
            red[ch][v] = a;
        }
        __syncthreads();
        if (tid < 32) {
            float a = p.outb[tid];
#pragma unroll
            for (int c = 0; c < 16; ++c) a += red[c][tid];
            lgs[tid] = a;
            p.vecO[((ll)blk * MLEN + s) * VV + tid] = a;
        }
        __syncthreads();
        if (tid == 0) {
            float best = lgs[0];
            int bi = 0;
#pragma unroll
            for (int v = 1; v < VV; ++v) {
                float val = lgs[v];
                if (val > best) { best = val; bi = v; }
            }
            tkn = bi;
        }
        cur ^= 1;
        __syncthreads();
    }

    // ================= final hidden [2][128][512] =================
    p.hidO[(ll)blk * HH + j] = h0m[cur][j];
    p.hidO[(ll)BB * HH + (ll)blk * HH + j] = h1m[cur][j];
}

extern "C" void kernel_launch(void* const* d_in, const int* in_sizes, int n_in,
                              void* d_out, int out_size, void* d_ws, size_t ws_size,
                              hipStream_t stream) {
    (void)in_sizes; (void)n_in; (void)out_size;
    P prm;
    prm.x     = (const float*)d_in[0];
    prm.emb   = (const float*)d_in[1];
    prm.eWih0 = (const float*)d_in[2];
    prm.eWhh0 = (const float*)d_in[3];
    prm.ebih0 = (const float*)d_in[4];
    prm.ebhh0 = (const float*)d_in[5];
    prm.eWih1 = (const float*)d_in[6];
    prm.eWhh1 = (const float*)d_in[7];
    prm.ebih1 = (const float*)d_in[8];
    prm.ebhh1 = (const float*)d_in[9];
    prm.dWih0 = (const float*)d_in[10];
    prm.dWhh0 = (const float*)d_in[11];
    prm.dbih0 = (const float*)d_in[12];
    prm.dbhh0 = (const float*)d_in[13];
    prm.dWih1 = (const float*)d_in[14];
    prm.dWhh1 = (const float*)d_in[15];
    prm.dbih1 = (const float*)d_in[16];
    prm.dbhh1 = (const float*)d_in[17];
    prm.qW    = (const float*)d_in[18];
    prm.qb    = (const float*)d_in[19];
    prm.outW  = (const float*)d_in[20];
    prm.outb  = (const float*)d_in[21];
    prm.ws    = (float*)d_ws;
    prm.vecO  = (float*)d_out;
    prm.hidO  = prm.vecO + (ll)BB * MLEN * VV;
    prm.attnO = prm.hidO + (ll)2 * BB * HH;

    if (ws_size >= (size_t)WS_NEED_BYTES) {
        hipLaunchKernelGGL(kprep, dim3(256), dim3(512), 0, stream, prm);
        hipLaunchKernelGGL(HIP_KERNEL_NAME(kmain<1>), dim3(NBLK), dim3(512), 0, stream, prm);
    } else {
        hipLaunchKernelGGL(HIP_KERNEL_NAME(kmain<0>), dim3(NBLK), dim3(512), 0, stream, prm);
    }
}

// Round 12
// 29972.144 us; speedup vs baseline: 2.1048x; 2.1048x over previous
//
#include <hip/hip_runtime.h>
#include <math.h>

#define BB 128
#define TT 256
#define HH 512
#define VV 32
#define MLEN 128
#define SLOT 65536          // HH*BB floats

// Static LDS layout (floats), 130048 bytes (R2-verified):
//  WT @0      : 24576  persistent weight tiles (enc: 36 rows x 512, dec: 24 rows x 1024)
//  QT @24576  : 2048   persistent qW tile (4 rows x 512)
//  PR @26624  : 1792   partial-sum rows (28 x 64)
//  SC @28416  : 4096   phase scratch (A2 softmax/attn staging stride-65, D logits staging)
#define WT_OFF 0
#define QT_OFF 24576
#define PR_OFF 26624
#define SC_OFF 28416
#define SM_FLOATS 32512

typedef long long ll;

struct P {
    const float *x, *emb;
    const float *eWih0, *eWhh0, *ebih0, *ebhh0;
    const float *eWih1, *eWhh1, *ebih1, *ebhh1;
    const float *dWih0, *dWhh0, *dbih0, *dbhh0;
    const float *dWih1, *dWhh1, *dbih1, *dbhh1;
    const float *qW, *qb, *outW, *outb;
    float *ws;
    float *vecO, *hidO, *attnO;
};

__device__ __forceinline__ float sigf(float v) { return 1.0f / (1.0f + __expf(-v)); }

// device-coherent (LLC) relaxed ops — producers write through to LLC
__device__ __forceinline__ float ldA(const float* p) {
    return __hip_atomic_load(p, __ATOMIC_RELAXED, __HIP_MEMORY_SCOPE_AGENT);
}
__device__ __forceinline__ void stA(float* p, float v) {
    __hip_atomic_store(p, v, __ATOMIC_RELAXED, __HIP_MEMORY_SCOPE_AGENT);
}
__device__ __forceinline__ int ldAi(const int* p) {
    return __hip_atomic_load(p, __ATOMIC_RELAXED, __HIP_MEMORY_SCOPE_AGENT);
}
__device__ __forceinline__ void stAi(int* p, int v) {
    __hip_atomic_store(p, v, __ATOMIC_RELAXED, __HIP_MEMORY_SCOPE_AGENT);
}

// relaxed-only two-level grid barrier (verified baseline)
__device__ __forceinline__ void gbar(int* W, int target) {
    __syncthreads();
    if (threadIdx.x == 0) {
        int par = target & 1;
        int g = blockIdx.x & 15;
        int* gc = W + 32 + (par * 16 + g) * 32;
        if (__hip_atomic_fetch_add(gc, 1, __ATOMIC_RELAXED, __HIP_MEMORY_SCOPE_AGENT) == 15) {
            __hip_atomic_store(gc, 0, __ATOMIC_RELAXED, __HIP_MEMORY_SCOPE_AGENT);
            int* rc = W + 1056 + par * 32;
            if (__hip_atomic_fetch_add(rc, 1, __ATOMIC_RELAXED, __HIP_MEMORY_SCOPE_AGENT) == 15) {
                __hip_atomic_store(rc, 0, __ATOMIC_RELAXED, __HIP_MEMORY_SCOPE_AGENT);
                __hip_atomic_store(W, target, __ATOMIC_RELAXED, __HIP_MEMORY_SCOPE_AGENT);
            }
        }
        while (__hip_atomic_load(W, __ATOMIC_RELAXED, __HIP_MEMORY_SCOPE_AGENT) < target)
            __builtin_amdgcn_s_sleep(2);
    }
    __syncthreads();
}

__global__ __launch_bounds__(512, 1) void kmain(P p) {
    __shared__ __align__(16) float smu[SM_FLOATS];
    const int tid = threadIdx.x;
    const int lane = tid & 63;
    const int wv = tid >> 6;
    const int blk = blockIdx.x;

    int* W = (int*)p.ws;
    int* tok = W + 4096;
    float* f = (float*)p.ws + 8192;
    float* eh0 = f;                       // 2 slots
    float* eh1 = f + 2 * SLOT;            // 2 slots
    float* inp = f + 4 * SLOT;            // ctx [512 d][128 b]
    float* qbm = f + 5 * SLOT;            // [512 j][128 b]
    float* scoresB = f + 6 * SLOT;        // [256 t][128 b]
    float* T = f + 6 * SLOT + SLOT / 2;   // [3][512][32] emb-projection table
    float* xT = T + 3 * HH * VV;          // [256 t][2][128 b]
    float* encO = f + (SLOT / 4) * 33;    // [256 t][512 j][128 b]

    const float4* t4 = (const float4*)smu;
    const float4* t4q = (const float4*)(smu + QT_OFF);

    const int jg = blk >> 1;              // 0..127, owns j = 4*jg..4*jg+3
    const int bh = blk & 1;
    const int b2 = bh * 64 + lane;
    int bar = 0;

    // ================= INIT =================
    {
        // zero 4 h slots
        stA(eh0 + blk * 1024 + tid, 0.0f);
        stA(eh0 + blk * 1024 + 512 + tid, 0.0f);
        // xT transpose
        if (tid < 256) {
            int idx = blk * 256 + tid;
            int t = idx >> 8, c = (idx >> 7) & 1, b = idx & 127;
            stA(xT + idx, p.x[((ll)b * TT + t) * 2 + c]);
        }
        // T table: T[(g*512+j)*32+v] = dot(dWih0[g*512+j][0:512], emb[v])
        if (tid < 192) {
            int unit = blk * 192 + tid;
            int v = unit & 31, gj = unit >> 5;
            const float* wrow = p.dWih0 + (ll)gj * 1024;
            const float* erow = p.emb + (ll)v * HH;
            float acc = 0.0f;
#pragma unroll 8
            for (int d = 0; d < HH; ++d) acc = fmaf(wrow[d], erow[d], acc);
            stA(T + unit, acc);
        }
        // persistent qW tile
#pragma unroll
        for (int jl = 0; jl < 4; ++jl)
            smu[QT_OFF + jl * 512 + tid] = p.qW[((ll)(jg * 4 + jl)) * HH + tid];
        // persistent encoder weights: rows 0..23 = (Whh0 g0..2 | Wih1 g0..2), 24..35 = Whh1
#pragma unroll
        for (int r = 0; r < 24; ++r) {
            int g = r >> 2, jl = r & 3, j = jg * 4 + jl;
            const float* src = (g < 3) ? (p.eWhh0 + (ll)(g * HH + j) * HH)
                                       : (p.eWih1 + (ll)((g - 3) * HH + j) * HH);
            smu[WT_OFF + r * 512 + tid] = src[tid];
        }
#pragma unroll
        for (int r = 0; r < 12; ++r) {
            int g = r >> 2, jl = r & 3, j = jg * 4 + jl;
            smu[WT_OFF + (24 + r) * 512 + tid] = p.eWhh1[(ll)(g * HH + j) * HH + tid];
        }
        gbar(W, ++bar);
    }

    // ================= ENCODER: 257 pipelined steps, single merged pass =================
    for (int t = 0; t <= TT; ++t) {
        const float* h0s = eh0 + (((t + 1) & 1) ? SLOT : 0);
        float*       h0d = eh0 + ((t & 1) ? SLOT : 0);
        const float* h1s = eh1 + (((t + 1) & 1) ? SLOT : 0);
        float*       h1d = eh1 + ((t & 1) ? SLOT : 0);

        smu[PR_OFF + tid] = 0.0f;
        smu[PR_OFF + 512 + tid] = 0.0f;
        smu[PR_OFF + 1024 + tid] = 0.0f;
        if (tid < 256) smu[PR_OFF + 1536 + tid] = 0.0f;
        __syncthreads();

        // merged stream, 2-deep register prefetch, rotated chunk order
        {
            const int rotE = jg & 7;
            const int ds0 = wv * 64;
            float acc[36];
#pragma unroll
            for (int r = 0; r < 36; ++r) acc[r] = 0.0f;
            float av[2][8], bv[2][8];
            {
                const int d0c = ds0 + rotE * 8;
#pragma unroll
                for (int u = 0; u < 8; ++u) av[0][u] = ldA(h0s + (ll)(d0c + u) * BB + b2);
#pragma unroll
                for (int u = 0; u < 8; ++u) bv[0][u] = ldA(h1s + (ll)(d0c + u) * BB + b2);
            }
#pragma unroll
            for (int c = 0; c < 8; ++c) {
                const int cb = c & 1, pb = cb ^ 1;
                if (c < 7) {
                    const int dn = ds0 + ((c + 1 + rotE) & 7) * 8;
#pragma unroll
                    for (int u = 0; u < 8; ++u) av[pb][u] = ldA(h0s + (ll)(dn + u) * BB + b2);
#pragma unroll
                    for (int u = 0; u < 8; ++u) bv[pb][u] = ldA(h1s + (ll)(dn + u) * BB + b2);
                }
                const int db = ds0 + ((c + rotE) & 7) * 8;
#pragma unroll
                for (int h2 = 0; h2 < 2; ++h2) {
                    const int q4 = (db + h2 * 4) >> 2;
#pragma unroll
                    for (int r = 0; r < 24; ++r) {
                        float4 w = t4[r * 128 + q4];
                        acc[r] = fmaf(w.x, av[cb][h2 * 4 + 0], acc[r]);
                        acc[r] = fmaf(w.y, av[cb][h2 * 4 + 1], acc[r]);
                        acc[r] = fmaf(w.z, av[cb][h2 * 4 + 2], acc[r]);
                        acc[r] = fmaf(w.w, av[cb][h2 * 4 + 3], acc[r]);
                    }
#pragma unroll
                    for (int r = 0; r < 12; ++r) {
                        float4 w = t4[(24 + r) * 128 + q4];
                        acc[24 + r] = fmaf(w.x, bv[cb][h2 * 4 + 0], acc[24 + r]);
                        acc[24 + r] = fmaf(w.y, bv[cb][h2 * 4 + 1], acc[24 + r]);
                        acc[24 + r] = fmaf(w.z, bv[cb][h2 * 4 + 2], acc[24 + r]);
                        acc[24 + r] = fmaf(w.w, bv[cb][h2 * 4 + 3], acc[24 + r]);
                    }
                }
            }
#pragma unroll
            for (int r = 0; r < 24; ++r)
                unsafeAtomicAdd(&smu[PR_OFF + r * 64 + lane], acc[r]);
#pragma unroll
            for (int r = 0; r < 12; ++r) {
                int g = r >> 2;
                int prow = (g < 2) ? (12 + g * 4) : 24;
                unsafeAtomicAdd(&smu[PR_OFF + (prow + (r & 3)) * 64 + lane], acc[24 + r]);
            }
        }
        __syncthreads();

        // finalize: waves 0..3 do layer0, waves 4..7 do layer1 (independent)
        if (wv < 4) {
            if (t < TT) {
                int jl = wv, j = jg * 4 + jl;
                float* pr = smu + PR_OFF;
                float hr = pr[(0 + jl) * 64 + lane] + p.ebhh0[j];
                float hz = pr[(4 + jl) * 64 + lane] + p.ebhh0[HH + j];
                float hn = pr[(8 + jl) * 64 + lane] + p.ebhh0[2 * HH + j];
                float x0 = xT[t * 256 + b2], x1 = xT[t * 256 + 128 + b2];
                float ir = fmaf(p.eWih0[j * 2], x0, fmaf(p.eWih0[j * 2 + 1], x1, p.ebih0[j]));
                float iz = fmaf(p.eWih0[(HH + j) * 2], x0, fmaf(p.eWih0[(HH + j) * 2 + 1], x1, p.ebih0[HH + j]));
                float in_ = fmaf(p.eWih0[(2 * HH + j) * 2], x0, fmaf(p.eWih0[(2 * HH + j) * 2 + 1], x1, p.ebih0[2 * HH + j]));
                float r = sigf(ir + hr), z = sigf(iz + hz);
                float n = tanhf(in_ + r * hn);
                float hp = ldA(h0s + (ll)j * BB + b2);
                stA(h0d + (ll)j * BB + b2, (1.0f - z) * n + z * hp);
            }
        } else if (t >= 1) {
            int jl = wv - 4, j = jg * 4 + jl;
            float* pr = smu + PR_OFF;
            float rs = pr[(12 + jl) * 64 + lane] + p.ebih1[j] + p.ebhh1[j];
            float zs = pr[(16 + jl) * 64 + lane] + p.ebih1[HH + j] + p.ebhh1[HH + j];
            float in1 = pr[(20 + jl) * 64 + lane] + p.ebih1[2 * HH + j];
            float hn1 = pr[(24 + jl) * 64 + lane] + p.ebhh1[2 * HH + j];
            float r = sigf(rs), z = sigf(zs);
            float n = tanhf(in1 + r * hn1);
            float hp = ldA(h1s + (ll)j * BB + b2);
            float hv = (1.0f - z) * n + z * hp;
            stA(h1d + (ll)j * BB + b2, hv);
            stA(encO + ((ll)(t - 1) * HH + j) * BB + b2, hv);
        }
        gbar(W, ++bar);
    }

    // ================= DEC-INIT: stage decoder weights + query from enc h1, tok=0 =================
    {
        const float* h1c = eh1;  // slot 0
        if (tid < 256) smu[PR_OFF + tid] = 0.0f;
        // persistent decoder weights: rows 0..11 = L0 (Wih0-ctx | Whh0), 12..23 = L1 (Wih1 | Whh1)
#pragma unroll
        for (int r = 0; r < 12; ++r) {
            int g = r >> 2, jl = r & 3, j = jg * 4 + jl;
            smu[WT_OFF + r * 1024 + tid]              = p.dWih0[(ll)(g * HH + j) * 1024 + 512 + tid];
            smu[WT_OFF + r * 1024 + 512 + tid]        = p.dWhh0[(ll)(g * HH + j) * HH + tid];
            smu[WT_OFF + (12 + r) * 1024 + tid]       = p.dWih1[(ll)(g * HH + j) * HH + tid];
            smu[WT_OFF + (12 + r) * 1024 + 512 + tid] = p.dWhh1[(ll)(g * HH + j) * HH + tid];
        }
        __syncthreads();
        {
            const int ds0 = wv * 64;
            float acc[4] = {0, 0, 0, 0};
            float av[8];
            for (int c = 0; c < 8; ++c) {
                int db = ds0 + c * 8;
#pragma unroll
                for (int u = 0; u < 8; ++u) av[u] = ldA(h1c + (ll)(db + u) * BB + b2);
#pragma unroll
                for (int h2 = 0; h2 < 2; ++h2) {
                    int q4 = (db + h2 * 4) >> 2;
#pragma unroll
                    for (int jl = 0; jl < 4; ++jl) {
                        float4 w = t4q[jl * 128 + q4];
                        acc[jl] = fmaf(w.x, av[h2 * 4 + 0], acc[jl]);
                        acc[jl] = fmaf(w.y, av[h2 * 4 + 1], acc[jl]);
                        acc[jl] = fmaf(w.z, av[h2 * 4 + 2], acc[jl]);
                        acc[jl] = fmaf(w.w, av[h2 * 4 + 3], acc[jl]);
                    }
                }
            }
#pragma unroll
            for (int jl = 0; jl < 4; ++jl)
                unsafeAtomicAdd(&smu[PR_OFF + jl * 64 + lane], acc[jl]);
        }
        __syncthreads();
        if (wv < 4) {
            int j = jg * 4 + wv;
            stA(qbm + (ll)j * BB + b2, smu[PR_OFF + wv * 64 + lane] + p.qb[j]);
        }
        if (blk == 128 && tid < BB) stAi(tok + tid, 0);
        gbar(W, ++bar);
    }

    // ================= DECODER: 128 steps x 5 phases =================
    for (int s = 0; s < MLEN; ++s) {
        const float* h0s = eh0 + (((s + 1) & 1) ? SLOT : 0);
        float*       g0d = eh0 + ((s & 1) ? SLOT : 0);
        const float* h1s = eh1 + ((s & 1) ? SLOT : 0);
        float*       h1d = eh1 + (((s + 1) & 1) ? SLOT : 0);

        // --- A1: scores, all 256 blocks, 2 t each (encO plain/cached; qbm LLC) ---
        {
            const int rotA = jg & 7;
            const int t0 = (blk >> 1) * 2;
            if (tid < 128) smu[PR_OFF + tid] = 0.0f;
            __syncthreads();
            const int js = wv * 64;
            float a0 = 0.0f, a1 = 0.0f;
            float qv[2][8], e0[2][8], e1[2][8];
            {
                const int j0 = js + rotA * 8;
#pragma unroll
                for (int u = 0; u < 8; ++u) {
                    qv[0][u] = ldA(qbm + (ll)(j0 + u) * BB + b2);
                    e0[0][u] = encO[((ll)t0 * HH + j0 + u) * BB + b2];
                    e1[0][u] = encO[((ll)(t0 + 1) * HH + j0 + u) * BB + b2];
                }
            }
#pragma unroll
            for (int c = 0; c < 8; ++c) {
                const int cb = c & 1, pb = cb ^ 1;
                if (c < 7) {
                    const int jn = js + ((c + 1 + rotA) & 7) * 8;
#pragma unroll
                    for (int u = 0; u < 8; ++u) {
                        qv[pb][u] = ldA(qbm + (ll)(jn + u) * BB + b2);
                        e0[pb][u] = encO[((ll)t0 * HH + jn + u) * BB + b2];
                        e1[pb][u] = encO[((ll)(t0 + 1) * HH + jn + u) * BB + b2];
                    }
                }
#pragma unroll
                for (int u = 0; u < 8; ++u) {
                    a0 = fmaf(qv[cb][u], e0[cb][u], a0);
                    a1 = fmaf(qv[cb][u], e1[cb][u], a1);
                }
            }
            unsafeAtomicAdd(&smu[PR_OFF + lane], a0);
            unsafeAtomicAdd(&smu[PR_OFF + 64 + lane], a1);
            __syncthreads();
            if (wv < 2)
                stA(scoresB + (ll)(t0 + wv) * BB + b2, smu[PR_OFF + wv * 64 + lane]);
        }
        gbar(W, ++bar);

        // --- A2: softmax + context (all 256 blocks); blocks<16 write attnO ---
        {
            const int d0 = jg * 4;
            float sv[32];
            for (int i = 0; i < 32; ++i) {
                int k = (i + (jg & 31)) & 31;
                sv[k] = ldA(scoresB + (ll)(wv * 32 + k) * BB + b2);
            }
            if (tid < 256) smu[PR_OFF + tid] = 0.0f;
            float mp = sv[0];
#pragma unroll
            for (int k = 1; k < 32; ++k) mp = fmaxf(mp, sv[k]);
            smu[SC_OFF + wv * 64 + lane] = mp;
            __syncthreads();
            float m = smu[SC_OFF + lane];
#pragma unroll
            for (int u = 1; u < 8; ++u) m = fmaxf(m, smu[SC_OFF + u * 64 + lane]);
            float e[32], lp = 0.0f;
#pragma unroll
            for (int k = 0; k < 32; ++k) { e[k] = __expf(sv[k] - m); lp += e[k]; }
            smu[SC_OFF + 512 + wv * 64 + lane] = lp;
            __syncthreads();
            float l = smu[SC_OFF + 512 + lane];
#pragma unroll
            for (int u = 1; u < 8; ++u) l += smu[SC_OFF + 512 + u * 64 + lane];
            float rl = 1.0f / l;
            if (blk < 16 && wv == jg) {
#pragma unroll
                for (int k = 0; k < 32; ++k) smu[SC_OFF + 1024 + k * 65 + lane] = e[k] * rl;
            }
            // context: chunked 2-deep prefetch, encO reads plain/cached
            float c4[4] = {0, 0, 0, 0};
            float ev[2][32];
#pragma unroll
            for (int u = 0; u < 8; ++u) {
                const float* Ep = encO + ((ll)(wv * 32 + u) * HH + d0) * BB + b2;
#pragma unroll
                for (int q = 0; q < 4; ++q) ev[0][u * 4 + q] = Ep[q * BB];
            }
#pragma unroll
            for (int kb = 0; kb < 4; ++kb) {
                const int cb = kb & 1, pb = cb ^ 1;
                if (kb < 3) {
#pragma unroll
                    for (int u = 0; u < 8; ++u) {
                        const float* Ep = encO + ((ll)(wv * 32 + (kb + 1) * 8 + u) * HH + d0) * BB + b2;
#pragma unroll
                        for (int q = 0; q < 4; ++q) ev[pb][u * 4 + q] = Ep[q * BB];
                    }
                }
#pragma unroll
                for (int u = 0; u < 8; ++u) {
                    const int k = kb * 8 + u;
                    c4[0] = fmaf(e[k], ev[cb][u * 4 + 0], c4[0]);
                    c4[1] = fmaf(e[k], ev[cb][u * 4 + 1], c4[1]);
                    c4[2] = fmaf(e[k], ev[cb][u * 4 + 2], c4[2]);
                    c4[3] = fmaf(e[k], ev[cb][u * 4 + 3], c4[3]);
                }
            }
#pragma unroll
            for (int kk = 0; kk < 4; ++kk)
                unsafeAtomicAdd(&smu[PR_OFF + kk * 64 + lane], c4[kk]);
            __syncthreads();
            if (tid < 256) {
                int kk = tid >> 6, ln = tid & 63;
                float l2 = smu[SC_OFF + 512 + ln];
#pragma unroll
                for (int u = 1; u < 8; ++u) l2 += smu[SC_OFF + 512 + u * 64 + ln];
                float val = smu[PR_OFF + kk * 64 + ln] / l2;
                stA(inp + (ll)(d0 + kk) * BB + bh * 64 + ln, val);
            }
            if (blk < 16) {
                int bi = tid >> 3, tj = tid & 7;
#pragma unroll
                for (int u = 0; u < 4; ++u) {
                    int tl = tj * 4 + u;
                    p.attnO[((ll)(bh * 64 + bi) * MLEN + s) * TT + jg * 32 + tl] = smu[SC_OFF + 1024 + tl * 65 + bi];
                }
            }
        }
        gbar(W, ++bar);

        // --- G0: decoder gru layer0 (K=1024: ctx then h0), rotated stream order ---
        {
            const int rotG = jg & 15;
            smu[PR_OFF + tid] = 0.0f;
            smu[PR_OFF + 512 + tid] = 0.0f;
            __syncthreads();
            const int ctxw = (wv < 4);
            const float* stream = ctxw ? inp : h0s;
            const int ds0 = (wv & 3) * 128;
            const int tb = ctxw ? 0 : 512;
            float acc[12];
#pragma unroll
            for (int r = 0; r < 12; ++r) acc[r] = 0.0f;
            float av[2][8];
            {
                const int d0c = ds0 + rotG * 8;
#pragma unroll
                for (int u = 0; u < 8; ++u) av[0][u] = ldA(stream + (ll)(d0c + u) * BB + b2);
            }
#pragma unroll
            for (int c = 0; c < 16; ++c) {
                const int cb = c & 1, pb = cb ^ 1;
                if (c < 15) {
                    const int dn = ds0 + ((c + 1 + rotG) & 15) * 8;
#pragma unroll
                    for (int u = 0; u < 8; ++u) av[pb][u] = ldA(stream + (ll)(dn + u) * BB + b2);
                }
                const int db = ds0 + ((c + rotG) & 15) * 8;
#pragma unroll
                for (int h2 = 0; h2 < 2; ++h2) {
                    const int q4 = (tb + db + h2 * 4) >> 2;
#pragma unroll
                    for (int r = 0; r < 12; ++r) {
                        float4 w = t4[r * 256 + q4];
                        acc[r] = fmaf(w.x, av[cb][h2 * 4 + 0], acc[r]);
                        acc[r] = fmaf(w.y, av[cb][h2 * 4 + 1], acc[r]);
                        acc[r] = fmaf(w.z, av[cb][h2 * 4 + 2], acc[r]);
                        acc[r] = fmaf(w.w, av[cb][h2 * 4 + 3], acc[r]);
                    }
                }
            }
#pragma unroll
            for (int r = 0; r < 12; ++r) {
                int g = r >> 2;
                int prow = (g < 2) ? g * 4 : (ctxw ? 8 : 12);
                unsafeAtomicAdd(&smu[PR_OFF + (prow + (r & 3)) * 64 + lane], acc[r]);
            }
            __syncthreads();
            if (wv < 4) {
                int jl = wv, j = jg * 4 + jl;
                float* pr = smu + PR_OFF;
                int tokb = ldAi(tok + b2);
                float rs = T[(ll)j * 32 + tokb] + pr[(0 + jl) * 64 + lane] + p.dbih0[j] + p.dbhh0[j];
                float zs = T[(ll)(HH + j) * 32 + tokb] + pr[(4 + jl) * 64 + lane] + p.dbih0[HH + j] + p.dbhh0[HH + j];
                float ins = T[(ll)(2 * HH + j) * 32 + tokb] + pr[(8 + jl) * 64 + lane] + p.dbih0[2 * HH + j];
                float hns = pr[(12 + jl) * 64 + lane] + p.dbhh0[2 * HH + j];
                float r = sigf(rs), z = sigf(zs);
                float n = tanhf(ins + r * hns);
                float hp = ldA(h0s + (ll)j * BB + b2);
                stA(g0d + (ll)j * BB + b2, (1.0f - z) * n + z * hp);
            }
        }
        gbar(W, ++bar);

        // --- G1: decoder gru layer1 (K=1024: g0 then h1), rotated stream order ---
        {
            const int rotG = jg & 15;
            smu[PR_OFF + tid] = 0.0f;
            smu[PR_OFF + 512 + tid] = 0.0f;
            __syncthreads();
            const int iw = (wv < 4);
            const float* stream = iw ? g0d : h1s;
            const int ds0 = (wv & 3) * 128;
            const int tb = iw ? 0 : 512;
            float acc[12];
#pragma unroll
            for (int r = 0; r < 12; ++r) acc[r] = 0.0f;
            float av[2][8];
            {
                const int d0c = ds0 + rotG * 8;
#pragma unroll
                for (int u = 0; u < 8; ++u) av[0][u] = ldA(stream + (ll)(d0c + u) * BB + b2);
            }
#pragma unroll
            for (int c = 0; c < 16; ++c) {
                const int cb = c & 1, pb = cb ^ 1;
                if (c < 15) {
                    const int dn = ds0 + ((c + 1 + rotG) & 15) * 8;
#pragma unroll
                    for (int u = 0; u < 8; ++u) av[pb][u] = ldA(stream + (ll)(dn + u) * BB + b2);
                }
                const int db = ds0 + ((c + rotG) & 15) * 8;
#pragma unroll
                for (int h2 = 0; h2 < 2; ++h2) {
                    const int q4 = (tb + db + h2 * 4) >> 2;
#pragma unroll
                    for (int r = 0; r < 12; ++r) {
                        float4 w = t4[(12 + r) * 256 + q4];
                        acc[r] = fmaf(w.x, av[cb][h2 * 4 + 0], acc[r]);
                        acc[r] = fmaf(w.y, av[cb][h2 * 4 + 1], acc[r]);
                        acc[r] = fmaf(w.z, av[cb][h2 * 4 + 2], acc[r]);
                        acc[r] = fmaf(w.w, av[cb][h2 * 4 + 3], acc[r]);
                    }
                }
            }
#pragma unroll
            for (int r = 0; r < 12; ++r) {
                int g = r >> 2;
                int prow = (g < 2) ? g * 4 : (iw ? 8 : 12);
                unsafeAtomicAdd(&smu[PR_OFF + (prow + (r & 3)) * 64 + lane], acc[r]);
            }
            __syncthreads();
            if (wv < 4) {
                int jl = wv, j = jg * 4 + jl;
                float* pr = smu + PR_OFF;
                float rs = pr[(0 + jl) * 64 + lane] + p.dbih1[j] + p.dbhh1[j];
                float zs = pr[(4 + jl) * 64 + lane] + p.dbih1[HH + j] + p.dbhh1[HH + j];
                float ins = pr[(8 + jl) * 64 + lane] + p.dbih1[2 * HH + j];
                float hns = pr[(12 + jl) * 64 + lane] + p.dbhh1[2 * HH + j];
                float r = sigf(rs), z = sigf(zs);
                float n = tanhf(ins + r * hns);
                float hp = ldA(h1s + (ll)j * BB + b2);
                stA(h1d + (ll)j * BB + b2, (1.0f - z) * n + z * hp);
            }
        }
        gbar(W, ++bar);

        // --- D: query (all blocks, rotated) + logits/argmax/tok (blocks 128..159, 4 b each) ---
        {
            const int rotD = jg & 7;
            const float* h1c = h1d;
            if (tid < 256) smu[PR_OFF + tid] = 0.0f;
            __syncthreads();
            {
                const int ds0 = wv * 64;
                float acc4[4] = {0, 0, 0, 0};
                float av[2][8];
                {
                    const int d0c = ds0 + rotD * 8;
#pragma unroll
                    for (int u = 0; u < 8; ++u) av[0][u] = ldA(h1c + (ll)(d0c + u) * BB + b2);
                }
#pragma unroll
                for (int c = 0; c < 8; ++c) {
                    const int cb = c & 1, pb = cb ^ 1;
                    if (c < 7) {
                        const int dn = ds0 + ((c + 1 + rotD) & 7) * 8;
#pragma unroll
                        for (int u = 0; u < 8; ++u) av[pb][u] = ldA(h1c + (ll)(dn + u) * BB + b2);
                    }
                    const int db = ds0 + ((c + rotD) & 7) * 8;
#pragma unroll
                    for (int h2 = 0; h2 < 2; ++h2) {
                        const int q4 = (db + h2 * 4) >> 2;
#pragma unroll
                        for (int jl = 0; jl < 4; ++jl) {
                            float4 w = t4q[jl * 128 + q4];
                            acc4[jl] = fmaf(w.x, av[cb][h2 * 4 + 0], acc4[jl]);
                            acc4[jl] = fmaf(w.y, av[cb][h2 * 4 + 1], acc4[jl]);
                            acc4[jl] = fmaf(w.z, av[cb][h2 * 4 + 2], acc4[jl]);
                            acc4[jl] = fmaf(w.w, av[cb][h2 * 4 + 3], acc4[jl]);
                        }
                    }
                }
#pragma unroll
                for (int jl = 0; jl < 4; ++jl)
                    unsafeAtomicAdd(&smu[PR_OFF + jl * 64 + lane], acc4[jl]);
            }
            __syncthreads();
            if (wv < 4) {
                int j = jg * 4 + wv;
                stA(qbm + (ll)j * BB + b2, smu[PR_OFF + wv * 64 + lane] + p.qb[j]);
            }
            if (blk >= 128 && blk < 160) {
                __syncthreads();
                const int bb = (blk - 128) * 4;
                // stage h1 slice [512 d][4 b] into SC
#pragma unroll
                for (int i = 0; i < 4; ++i) {
                    int f2 = i * 512 + tid;
                    int d = f2 >> 2, bi2 = f2 & 3;
                    smu[SC_OFF + f2] = ldA(h1c + (ll)d * BB + bb + bi2);
                }
                __syncthreads();
                if (tid < 128) {
                    const int bl = tid >> 5, v = tid & 31;
                    float acc = 0.0f;
                    for (int d4 = 0; d4 < 128; ++d4) {
                        float4 w4 = *(const float4*)(p.outW + (ll)v * HH + d4 * 4);
                        acc = fmaf(w4.x, smu[SC_OFF + (d4 * 4 + 0) * 4 + bl], acc);
                        acc = fmaf(w4.y, smu[SC_OFF + (d4 * 4 + 1) * 4 + bl], acc);
                        acc = fmaf(w4.z, smu[SC_OFF + (d4 * 4 + 2) * 4 + bl], acc);
                        acc = fmaf(w4.w, smu[SC_OFF + (d4 * 4 + 3) * 4 + bl], acc);
                    }
                    acc += p.outb[v];
                    p.vecO[((ll)(bb + bl) * MLEN + s) * VV + v] = acc;
                    smu[SC_OFF + 2048 + tid] = acc;
                }
                __syncthreads();
                if (tid < 4) {
                    int base = SC_OFF + 2048 + tid * 32;
                    float best = smu[base];
                    int bi2 = 0;
#pragma unroll
                    for (int u = 1; u < 32; ++u) {
                        float val = smu[base + u];
                        if (val > best) { best = val; bi2 = u; }
                    }
                    stAi(tok + bb + tid, bi2);
                }
            }
        }
        gbar(W, ++bar);
    }

    // ================= final hidden [2][128][512] =================
    {
        int idx = blk * 512 + tid;
        int l = idx >> 16, rr = idx & 65535;
        int b = rr >> 9, h = rr & 511;
        const float* src = l ? eh1 : (eh0 + SLOT);
        p.hidO[idx] = ldA(src + (ll)h * BB + b);
    }
}

extern "C" void kernel_launch(void* const* d_in, const int* in_sizes, int n_in,
                              void* d_out, int out_size, void* d_ws, size_t ws_size,
                              hipStream_t stream) {
    (void)in_sizes; (void)n_in; (void)out_size; (void)ws_size;
    P prm;
    prm.x     = (const float*)d_in[0];
    prm.emb   = (const float*)d_in[1];
    prm.eWih0 = (const float*)d_in[2];
    prm.eWhh0 = (const float*)d_in[3];
    prm.ebih0 = (const float*)d_in[4];
    prm.ebhh0 = (const float*)d_in[5];
    prm.eWih1 = (const float*)d_in[6];
    prm.eWhh1 = (const float*)d_in[7];
    prm.ebih1 = (const float*)d_in[8];
    prm.ebhh1 = (const float*)d_in[9];
    prm.dWih0 = (const float*)d_in[10];
    prm.dWhh0 = (const float*)d_in[11];
    prm.dbih0 = (const float*)d_in[12];
    prm.dbhh0 = (const float*)d_in[13];
    prm.dWih1 = (const float*)d_in[14];
    prm.dWhh1 = (const float*)d_in[15];
    prm.dbih1 = (const float*)d_in[16];
    prm.dbhh1 = (const float*)d_in[17];
    prm.qW    = (const float*)d_in[18];
    prm.qb    = (const float*)d_in[19];
    prm.outW  = (const float*)d_in[20];
    prm.outb  = (const float*)d_in[21];
    prm.ws    = (float*)d_ws;
    prm.vecO  = (float*)d_out;
    prm.hidO  = prm.vecO + (ll)BB * MLEN * VV;
    prm.attnO = prm.hidO + (ll)2 * BB * HH;

    hipMemsetAsync(d_ws, 0, 16384, stream);  // barrier gen + tree counters
    void* args[] = { &prm };
    hipLaunchCooperativeKernel((void*)kmain, dim3(256), dim3(512), args, 0, stream);
}

// Round 13
// 29445.599 us; speedup vs baseline: 2.1424x; 1.0179x over previous
//
#include <hip/hip_runtime.h>
#include <math.h>

#define BB 128
#define TT 256
#define HH 512
#define VV 32
#define MLEN 128
#define SLOT 65536          // HH*BB floats

// Static LDS layout (floats), 130048 bytes (R2-verified):
#define WT_OFF 0
#define QT_OFF 24576
#define PR_OFF 26624
#define SC_OFF 28416
#define SM_FLOATS 32512

// pair-packed layouts: element (d,b) of a [dim][128] buffer lives at
// (d/2)*256 + b*2 + (d&1)  -> adjacent dims for one b are contiguous 8 B
#define HX(d, b) ((((d) >> 1) << 8) + ((b) << 1) + ((d) & 1))
#define SX(t, b) ((((t) >> 1) << 8) + ((b) << 1) + ((t) & 1))
#define EX(t, j, b) ((ll)(t) * (HH * BB) + (((j) >> 1) << 8) + ((b) << 1) + ((j) & 1))

typedef long long ll;

struct P {
    const float *x, *emb;
    const float *eWih0, *eWhh0, *ebih0, *ebhh0;
    const float *eWih1, *eWhh1, *ebih1, *ebhh1;
    const float *dWih0, *dWhh0, *dbih0, *dbhh0;
    const float *dWih1, *dWhh1, *dbih1, *dbhh1;
    const float *qW, *qb, *outW, *outb;
    float *ws;
    float *vecO, *hidO, *attnO;
};

__device__ __forceinline__ float sigf(float v) { return 1.0f / (1.0f + __expf(-v)); }

// device-coherent (LLC) relaxed ops
__device__ __forceinline__ float ldA(const float* p) {
    return __hip_atomic_load(p, __ATOMIC_RELAXED, __HIP_MEMORY_SCOPE_AGENT);
}
__device__ __forceinline__ float2 ldA2(const float* p) {
    unsigned long long v = __hip_atomic_load((const unsigned long long*)p,
                                             __ATOMIC_RELAXED, __HIP_MEMORY_SCOPE_AGENT);
    union { unsigned long long u; float2 f; } c; c.u = v; return c.f;
}
__device__ __forceinline__ void stA(float* p, float v) {
    __hip_atomic_store(p, v, __ATOMIC_RELAXED, __HIP_MEMORY_SCOPE_AGENT);
}
__device__ __forceinline__ int ldAi(const int* p) {
    return __hip_atomic_load(p, __ATOMIC_RELAXED, __HIP_MEMORY_SCOPE_AGENT);
}
__device__ __forceinline__ void stAi(int* p, int v) {
    __hip_atomic_store(p, v, __ATOMIC_RELAXED, __HIP_MEMORY_SCOPE_AGENT);
}

// relaxed-only two-level grid barrier (verified baseline)
__device__ __forceinline__ void gbar(int* W, int target) {
    __syncthreads();
    if (threadIdx.x == 0) {
        int par = target & 1;
        int g = blockIdx.x & 15;
        int* gc = W + 32 + (par * 16 + g) * 32;
        if (__hip_atomic_fetch_add(gc, 1, __ATOMIC_RELAXED, __HIP_MEMORY_SCOPE_AGENT) == 15) {
            __hip_atomic_store(gc, 0, __ATOMIC_RELAXED, __HIP_MEMORY_SCOPE_AGENT);
            int* rc = W + 1056 + par * 32;
            if (__hip_atomic_fetch_add(rc, 1, __ATOMIC_RELAXED, __HIP_MEMORY_SCOPE_AGENT) == 15) {
                __hip_atomic_store(rc, 0, __ATOMIC_RELAXED, __HIP_MEMORY_SCOPE_AGENT);
                __hip_atomic_store(W, target, __ATOMIC_RELAXED, __HIP_MEMORY_SCOPE_AGENT);
            }
        }
        while (__hip_atomic_load(W, __ATOMIC_RELAXED, __HIP_MEMORY_SCOPE_AGENT) < target)
            __builtin_amdgcn_s_sleep(2);
    }
    __syncthreads();
}

__global__ __launch_bounds__(512, 1) void kmain(P p) {
    __shared__ __align__(16) float smu[SM_FLOATS];
    const int tid = threadIdx.x;
    const int lane = tid & 63;
    const int wv = tid >> 6;
    const int blk = blockIdx.x;

    int* W = (int*)p.ws;
    int* tok = W + 4096;
    float* f = (float*)p.ws + 8192;
    float* eh0 = f;                       // 2 slots, pair-packed
    float* eh1 = f + 2 * SLOT;            // 2 slots, pair-packed
    float* inp = f + 4 * SLOT;            // ctx, pair-packed
    float* qbm = f + 5 * SLOT;            // pair-packed
    float* scoresB = f + 6 * SLOT;        // pair-packed over t
    float* T = f + 6 * SLOT + SLOT / 2;   // [3][512][32] emb-projection table
    float* xT = T + 3 * HH * VV;          // [256 t][2][128 b]
    float* encO = f + (SLOT / 4) * 33;    // pair-packed: EX(t,j,b)

    const float4* t4 = (const float4*)smu;
    const float4* t4q = (const float4*)(smu + QT_OFF);

    const int jg = blk >> 1;              // 0..127, owns j = 4*jg..4*jg+3
    const int bh = blk & 1;
    const int b2 = bh * 64 + lane;
    int bar = 0;

    // ================= INIT =================
    {
        stA(eh0 + blk * 1024 + tid, 0.0f);
        stA(eh0 + blk * 1024 + 512 + tid, 0.0f);
        if (tid < 256) {
            int idx = blk * 256 + tid;
            int t = idx >> 8, c = (idx >> 7) & 1, b = idx & 127;
            stA(xT + idx, p.x[((ll)b * TT + t) * 2 + c]);
        }
        if (tid < 192) {
            int unit = blk * 192 + tid;
            int v = unit & 31, gj = unit >> 5;
            const float* wrow = p.dWih0 + (ll)gj * 1024;
            const float* erow = p.emb + (ll)v * HH;
            float acc = 0.0f;
#pragma unroll 8
            for (int d = 0; d < HH; ++d) acc = fmaf(wrow[d], erow[d], acc);
            stA(T + unit, acc);
        }
#pragma unroll
        for (int jl = 0; jl < 4; ++jl)
            smu[QT_OFF + jl * 512 + tid] = p.qW[((ll)(jg * 4 + jl)) * HH + tid];
#pragma unroll
        for (int r = 0; r < 24; ++r) {
            int g = r >> 2, jl = r & 3, j = jg * 4 + jl;
            const float* src = (g < 3) ? (p.eWhh0 + (ll)(g * HH + j) * HH)
                                       : (p.eWih1 + (ll)((g - 3) * HH + j) * HH);
            smu[WT_OFF + r * 512 + tid] = src[tid];
        }
#pragma unroll
        for (int r = 0; r < 12; ++r) {
            int g = r >> 2, jl = r & 3, j = jg * 4 + jl;
            smu[WT_OFF + (24 + r) * 512 + tid] = p.eWhh1[(ll)(g * HH + j) * HH + tid];
        }
        gbar(W, ++bar);
    }

    // ================= ENCODER: 257 pipelined steps =================
    for (int t = 0; t <= TT; ++t) {
        const float* h0s = eh0 + (((t + 1) & 1) ? SLOT : 0);
        float*       h0d = eh0 + ((t & 1) ? SLOT : 0);
        const float* h1s = eh1 + (((t + 1) & 1) ? SLOT : 0);
        float*       h1d = eh1 + ((t & 1) ? SLOT : 0);

        smu[PR_OFF + tid] = 0.0f;
        smu[PR_OFF + 512 + tid] = 0.0f;
        smu[PR_OFF + 1024 + tid] = 0.0f;
        if (tid < 256) smu[PR_OFF + 1536 + tid] = 0.0f;
        __syncthreads();

        // merged stream, 2-deep prefetch, pair loads
        {
            const int rotE = jg & 7;
            const int ds0 = wv * 64;
            float acc[36];
#pragma unroll
            for (int r = 0; r < 36; ++r) acc[r] = 0.0f;
            float av[2][8], bv[2][8];
            {
                const int d0c = ds0 + rotE * 8;
#pragma unroll
                for (int k = 0; k < 4; ++k) {
                    float2 va = ldA2(h0s + HX(d0c + 2 * k, b2));
                    av[0][2 * k] = va.x; av[0][2 * k + 1] = va.y;
                    float2 vb = ldA2(h1s + HX(d0c + 2 * k, b2));
                    bv[0][2 * k] = vb.x; bv[0][2 * k + 1] = vb.y;
                }
            }
#pragma unroll
            for (int c = 0; c < 8; ++c) {
                const int cb = c & 1, pb = cb ^ 1;
                if (c < 7) {
                    const int dn = ds0 + ((c + 1 + rotE) & 7) * 8;
#pragma unroll
                    for (int k = 0; k < 4; ++k) {
                        float2 va = ldA2(h0s + HX(dn + 2 * k, b2));
                        av[pb][2 * k] = va.x; av[pb][2 * k + 1] = va.y;
                        float2 vb = ldA2(h1s + HX(dn + 2 * k, b2));
                        bv[pb][2 * k] = vb.x; bv[pb][2 * k + 1] = vb.y;
                    }
                }
                const int db = ds0 + ((c + rotE) & 7) * 8;
#pragma unroll
                for (int h2 = 0; h2 < 2; ++h2) {
                    const int q4 = (db + h2 * 4) >> 2;
#pragma unroll
                    for (int r = 0; r < 24; ++r) {
                        float4 w = t4[r * 128 + q4];
                        acc[r] = fmaf(w.x, av[cb][h2 * 4 + 0], acc[r]);
                        acc[r] = fmaf(w.y, av[cb][h2 * 4 + 1], acc[r]);
                        acc[r] = fmaf(w.z, av[cb][h2 * 4 + 2], acc[r]);
                        acc[r] = fmaf(w.w, av[cb][h2 * 4 + 3], acc[r]);
                    }
#pragma unroll
                    for (int r = 0; r < 12; ++r) {
                        float4 w = t4[(24 + r) * 128 + q4];
                        acc[24 + r] = fmaf(w.x, bv[cb][h2 * 4 + 0], acc[24 + r]);
                        acc[24 + r] = fmaf(w.y, bv[cb][h2 * 4 + 1], acc[24 + r]);
                        acc[24 + r] = fmaf(w.z, bv[cb][h2 * 4 + 2], acc[24 + r]);
                        acc[24 + r] = fmaf(w.w, bv[cb][h2 * 4 + 3], acc[24 + r]);
                    }
                }
            }
#pragma unroll
            for (int r = 0; r < 24; ++r)
                unsafeAtomicAdd(&smu[PR_OFF + r * 64 + lane], acc[r]);
#pragma unroll
            for (int r = 0; r < 12; ++r) {
                int g = r >> 2;
                int prow = (g < 2) ? (12 + g * 4) : 24;
                unsafeAtomicAdd(&smu[PR_OFF + (prow + (r & 3)) * 64 + lane], acc[24 + r]);
            }
        }
        __syncthreads();

        if (wv < 4) {
            if (t < TT) {
                int jl = wv, j = jg * 4 + jl;
                float* pr = smu + PR_OFF;
                float hr = pr[(0 + jl) * 64 + lane] + p.ebhh0[j];
                float hz = pr[(4 + jl) * 64 + lane] + p.ebhh0[HH + j];
                float hn = pr[(8 + jl) * 64 + lane] + p.ebhh0[2 * HH + j];
                float x0 = xT[t * 256 + b2], x1 = xT[t * 256 + 128 + b2];
                float ir = fmaf(p.eWih0[j * 2], x0, fmaf(p.eWih0[j * 2 + 1], x1, p.ebih0[j]));
                float iz = fmaf(p.eWih0[(HH + j) * 2], x0, fmaf(p.eWih0[(HH + j) * 2 + 1], x1, p.ebih0[HH + j]));
                float in_ = fmaf(p.eWih0[(2 * HH + j) * 2], x0, fmaf(p.eWih0[(2 * HH + j) * 2 + 1], x1, p.ebih0[2 * HH + j]));
                float r = sigf(ir + hr), z = sigf(iz + hz);
                float n = tanhf(in_ + r * hn);
                float hp = ldA(h0s + HX(j, b2));
                stA(h0d + HX(j, b2), (1.0f - z) * n + z * hp);
            }
        } else if (t >= 1) {
            int jl = wv - 4, j = jg * 4 + jl;
            float* pr = smu + PR_OFF;
            float rs = pr[(12 + jl) * 64 + lane] + p.ebih1[j] + p.ebhh1[j];
            float zs = pr[(16 + jl) * 64 + lane] + p.ebih1[HH + j] + p.ebhh1[HH + j];
            float in1 = pr[(20 + jl) * 64 + lane] + p.ebih1[2 * HH + j];
            float hn1 = pr[(24 + jl) * 64 + lane] + p.ebhh1[2 * HH + j];
            float r = sigf(rs), z = sigf(zs);
            float n = tanhf(in1 + r * hn1);
            float hp = ldA(h1s + HX(j, b2));
            float hv = (1.0f - z) * n + z * hp;
            stA(h1d + HX(j, b2), hv);
            stA(encO + EX(t - 1, j, b2), hv);
        }
        gbar(W, ++bar);
    }

    // ================= DEC-INIT =================
    {
        const float* h1c = eh1;  // slot 0
        if (tid < 256) smu[PR_OFF + tid] = 0.0f;
#pragma unroll
        for (int r = 0; r < 12; ++r) {
            int g = r >> 2, jl = r & 3, j = jg * 4 + jl;
            smu[WT_OFF + r * 1024 + tid]              = p.dWih0[(ll)(g * HH + j) * 1024 + 512 + tid];
            smu[WT_OFF + r * 1024 + 512 + tid]        = p.dWhh0[(ll)(g * HH + j) * HH + tid];
            smu[WT_OFF + (12 + r) * 1024 + tid]       = p.dWih1[(ll)(g * HH + j) * HH + tid];
            smu[WT_OFF + (12 + r) * 1024 + 512 + tid] = p.dWhh1[(ll)(g * HH + j) * HH + tid];
        }
        __syncthreads();
        {
            const int ds0 = wv * 64;
            float acc[4] = {0, 0, 0, 0};
            float av[8];
            for (int c = 0; c < 8; ++c) {
                int db = ds0 + c * 8;
#pragma unroll
                for (int k = 0; k < 4; ++k) {
                    float2 v = ldA2(h1c + HX(db + 2 * k, b2));
                    av[2 * k] = v.x; av[2 * k + 1] = v.y;
                }
#pragma unroll
                for (int h2 = 0; h2 < 2; ++h2) {
                    int q4 = (db + h2 * 4) >> 2;
#pragma unroll
                    for (int jl = 0; jl < 4; ++jl) {
                        float4 w = t4q[jl * 128 + q4];
                        acc[jl] = fmaf(w.x, av[h2 * 4 + 0], acc[jl]);
                        acc[jl] = fmaf(w.y, av[h2 * 4 + 1], acc[jl]);
                        acc[jl] = fmaf(w.z, av[h2 * 4 + 2], acc[jl]);
                        acc[jl] = fmaf(w.w, av[h2 * 4 + 3], acc[jl]);
                    }
                }
            }
#pragma unroll
            for (int jl = 0; jl < 4; ++jl)
                unsafeAtomicAdd(&smu[PR_OFF + jl * 64 + lane], acc[jl]);
        }
        __syncthreads();
        if (wv < 4) {
            int j = jg * 4 + wv;
            stA(qbm + HX(j, b2), smu[PR_OFF + wv * 64 + lane] + p.qb[j]);
        }
        if (blk == 128 && tid < BB) stAi(tok + tid, 0);
        gbar(W, ++bar);
    }

    // ================= DECODER: 128 steps x 5 phases =================
    for (int s = 0; s < MLEN; ++s) {
        const float* h0s = eh0 + (((s + 1) & 1) ? SLOT : 0);
        float*       g0d = eh0 + ((s & 1) ? SLOT : 0);
        const float* h1s = eh1 + ((s & 1) ? SLOT : 0);
        float*       h1d = eh1 + (((s + 1) & 1) ? SLOT : 0);

        // --- A1: scores, pair loads ---
        {
            const int rotA = jg & 7;
            const int t0 = (blk >> 1) * 2;
            if (tid < 128) smu[PR_OFF + tid] = 0.0f;
            __syncthreads();
            const int js = wv * 64;
            float a0 = 0.0f, a1 = 0.0f;
            float qv[2][8], e0[2][8], e1[2][8];
            {
                const int j0 = js + rotA * 8;
                const float* eb0 = encO + (ll)t0 * (HH * BB) + ((j0 >> 1) << 8) + (b2 << 1);
                const float* eb1 = encO + (ll)(t0 + 1) * (HH * BB) + ((j0 >> 1) << 8) + (b2 << 1);
#pragma unroll
                for (int k = 0; k < 4; ++k) {
                    float2 q2 = ldA2(qbm + HX(j0 + 2 * k, b2));
                    qv[0][2 * k] = q2.x; qv[0][2 * k + 1] = q2.y;
                    float2 v0 = *(const float2*)(eb0 + k * 256);
                    e0[0][2 * k] = v0.x; e0[0][2 * k + 1] = v0.y;
                    float2 v1 = *(const float2*)(eb1 + k * 256);
                    e1[0][2 * k] = v1.x; e1[0][2 * k + 1] = v1.y;
                }
            }
#pragma unroll
            for (int c = 0; c < 8; ++c) {
                const int cb = c & 1, pb = cb ^ 1;
                if (c < 7) {
                    const int jn = js + ((c + 1 + rotA) & 7) * 8;
                    const float* eb0 = encO + (ll)t0 * (HH * BB) + ((jn >> 1) << 8) + (b2 << 1);
                    const float* eb1 = encO + (ll)(t0 + 1) * (HH * BB) + ((jn >> 1) << 8) + (b2 << 1);
#pragma unroll
                    for (int k = 0; k < 4; ++k) {
                        float2 q2 = ldA2(qbm + HX(jn + 2 * k, b2));
                        qv[pb][2 * k] = q2.x; qv[pb][2 * k + 1] = q2.y;
                        float2 v0 = *(const float2*)(eb0 + k * 256);
                        e0[pb][2 * k] = v0.x; e0[pb][2 * k + 1] = v0.y;
                        float2 v1 = *(const float2*)(eb1 + k * 256);
                        e1[pb][2 * k] = v1.x; e1[pb][2 * k + 1] = v1.y;
                    }
                }
#pragma unroll
                for (int u = 0; u < 8; ++u) {
                    a0 = fmaf(qv[cb][u], e0[cb][u], a0);
                    a1 = fmaf(qv[cb][u], e1[cb][u], a1);
                }
            }
            unsafeAtomicAdd(&smu[PR_OFF + lane], a0);
            unsafeAtomicAdd(&smu[PR_OFF + 64 + lane], a1);
            __syncthreads();
            if (wv < 2)
                stA(scoresB + SX(t0 + wv, b2), smu[PR_OFF + wv * 64 + lane]);
        }
        gbar(W, ++bar);

        // --- A2: softmax + context ---
        {
            const int d0 = jg * 4;
            float sv[32];
#pragma unroll
            for (int kp = 0; kp < 16; ++kp) {
                float2 v = ldA2(scoresB + ((wv * 16 + kp) << 8) + (b2 << 1));
                sv[2 * kp] = v.x; sv[2 * kp + 1] = v.y;
            }
            if (tid < 256) smu[PR_OFF + tid] = 0.0f;
            float mp = sv[0];
#pragma unroll
            for (int k = 1; k < 32; ++k) mp = fmaxf(mp, sv[k]);
            smu[SC_OFF + wv * 64 + lane] = mp;
            __syncthreads();
            float m = smu[SC_OFF + lane];
#pragma unroll
            for (int u = 1; u < 8; ++u) m = fmaxf(m, smu[SC_OFF + u * 64 + lane]);
            float e[32], lp = 0.0f;
#pragma unroll
            for (int k = 0; k < 32; ++k) { e[k] = __expf(sv[k] - m); lp += e[k]; }
            smu[SC_OFF + 512 + wv * 64 + lane] = lp;
            __syncthreads();
            float l = smu[SC_OFF + 512 + lane];
#pragma unroll
            for (int u = 1; u < 8; ++u) l += smu[SC_OFF + 512 + u * 64 + lane];
            float rl = 1.0f / l;
            if (blk < 16 && wv == jg) {
#pragma unroll
                for (int k = 0; k < 32; ++k) smu[SC_OFF + 1024 + k * 65 + lane] = e[k] * rl;
            }
            // context: pair loads from encO (d0..d0+3 contiguous pairs)
            float c4[4] = {0, 0, 0, 0};
            float ev[2][32];
#pragma unroll
            for (int u = 0; u < 8; ++u) {
                const float* Ep = encO + (ll)(wv * 32 + u) * (HH * BB) + ((d0 >> 1) << 8) + (b2 << 1);
                float2 pa = *(const float2*)(Ep);
                float2 pb2 = *(const float2*)(Ep + 256);
                ev[0][u * 4 + 0] = pa.x; ev[0][u * 4 + 1] = pa.y;
                ev[0][u * 4 + 2] = pb2.x; ev[0][u * 4 + 3] = pb2.y;
            }
#pragma unroll
            for (int kb = 0; kb < 4; ++kb) {
                const int cb = kb & 1, pb = cb ^ 1;
                if (kb < 3) {
#pragma unroll
                    for (int u = 0; u < 8; ++u) {
                        const float* Ep = encO + (ll)(wv * 32 + (kb + 1) * 8 + u) * (HH * BB) + ((d0 >> 1) << 8) + (b2 << 1);
                        float2 pa = *(const float2*)(Ep);
                        float2 pb2 = *(const float2*)(Ep + 256);
                        ev[pb][u * 4 + 0] = pa.x; ev[pb][u * 4 + 1] = pa.y;
                        ev[pb][u * 4 + 2] = pb2.x; ev[pb][u * 4 + 3] = pb2.y;
                    }
                }
#pragma unroll
                for (int u = 0; u < 8; ++u) {
                    const int k = kb * 8 + u;
                    c4[0] = fmaf(e[k], ev[cb][u * 4 + 0], c4[0]);
                    c4[1] = fmaf(e[k], ev[cb][u * 4 + 1], c4[1]);
                    c4[2] = fmaf(e[k], ev[cb][u * 4 + 2], c4[2]);
                    c4[3] = fmaf(e[k], ev[cb][u * 4 + 3], c4[3]);
                }
            }
#pragma unroll
            for (int kk = 0; kk < 4; ++kk)
                unsafeAtomicAdd(&smu[PR_OFF + kk * 64 + lane], c4[kk]);
            __syncthreads();
            if (tid < 256) {
                int kk = tid >> 6, ln = tid & 63;
                float l2 = smu[SC_OFF + 512 + ln];
#pragma unroll
                for (int u = 1; u < 8; ++u) l2 += smu[SC_OFF + 512 + u * 64 + ln];
                float val = smu[PR_OFF + kk * 64 + ln] / l2;
                stA(inp + HX(d0 + kk, bh * 64 + ln), val);
            }
            if (blk < 16) {
                int bi = tid >> 3, tj = tid & 7;
#pragma unroll
                for (int u = 0; u < 4; ++u) {
                    int tl = tj * 4 + u;
                    p.attnO[((ll)(bh * 64 + bi) * MLEN + s) * TT + jg * 32 + tl] = smu[SC_OFF + 1024 + tl * 65 + bi];
                }
            }
        }
        gbar(W, ++bar);

        // --- G0 ---
        {
            const int rotG = jg & 15;
            smu[PR_OFF + tid] = 0.0f;
            smu[PR_OFF + 512 + tid] = 0.0f;
            __syncthreads();
            const int ctxw = (wv < 4);
            const float* stream = ctxw ? inp : h0s;
            const int ds0 = (wv & 3) * 128;
            const int tb = ctxw ? 0 : 512;
            float acc[12];
#pragma unroll
            for (int r = 0; r < 12; ++r) acc[r] = 0.0f;
            float av[2][8];
            {
                const int d0c = ds0 + rotG * 8;
#pragma unroll
                for (int k = 0; k < 4; ++k) {
                    float2 v = ldA2(stream + HX(d0c + 2 * k, b2));
                    av[0][2 * k] = v.x; av[0][2 * k + 1] = v.y;
                }
            }
#pragma unroll
            for (int c = 0; c < 16; ++c) {
                const int cb = c & 1, pb = cb ^ 1;
                if (c < 15) {
                    const int dn = ds0 + ((c + 1 + rotG) & 15) * 8;
#pragma unroll
                    for (int k = 0; k < 4; ++k) {
                        float2 v = ldA2(stream + HX(dn + 2 * k, b2));
                        av[pb][2 * k] = v.x; av[pb][2 * k + 1] = v.y;
                    }
                }
                const int db = ds0 + ((c + rotG) & 15) * 8;
#pragma unroll
                for (int h2 = 0; h2 < 2; ++h2) {
                    const int q4 = (tb + db + h2 * 4) >> 2;
#pragma unroll
                    for (int r = 0; r < 12; ++r) {
                        float4 w = t4[r * 256 + q4];
                        acc[r] = fmaf(w.x, av[cb][h2 * 4 + 0], acc[r]);
                        acc[r] = fmaf(w.y, av[cb][h2 * 4 + 1], acc[r]);
                        acc[r] = fmaf(w.z, av[cb][h2 * 4 + 2], acc[r]);
                        acc[r] = fmaf(w.w, av[cb][h2 * 4 + 3], acc[r]);
                    }
                }
            }
#pragma unroll
            for (int r = 0; r < 12; ++r) {
                int g = r >> 2;
                int prow = (g < 2) ? g * 4 : (ctxw ? 8 : 12);
                unsafeAtomicAdd(&smu[PR_OFF + (prow + (r & 3)) * 64 + lane], acc[r]);
            }
            __syncthreads();
            if (wv < 4) {
                int jl = wv, j = jg * 4 + jl;
                float* pr = smu + PR_OFF;
                int tokb = ldAi(tok + b2);
                float rs = T[(ll)j * 32 + tokb] + pr[(0 + jl) * 64 + lane] + p.dbih0[j] + p.dbhh0[j];
                float zs = T[(ll)(HH + j) * 32 + tokb] + pr[(4 + jl) * 64 + lane] + p.dbih0[HH + j] + p.dbhh0[HH + j];
                float ins = T[(ll)(2 * HH + j) * 32 + tokb] + pr[(8 + jl) * 64 + lane] + p.dbih0[2 * HH + j];
                float hns = pr[(12 + jl) * 64 + lane] + p.dbhh0[2 * HH + j];
                float r = sigf(rs), z = sigf(zs);
                float n = tanhf(ins + r * hns);
                float hp = ldA(h0s + HX(j, b2));
                stA(g0d + HX(j, b2), (1.0f - z) * n + z * hp);
            }
        }
        gbar(W, ++bar);

        // --- G1 ---
        {
            const int rotG = jg & 15;
            smu[PR_OFF + tid] = 0.0f;
            smu[PR_OFF + 512 + tid] = 0.0f;
            __syncthreads();
            const int iw = (wv < 4);
            const float* stream = iw ? g0d : h1s;
            const int ds0 = (wv & 3) * 128;
            const int tb = iw ? 0 : 512;
            float acc[12];
#pragma unroll
            for (int r = 0; r < 12; ++r) acc[r] = 0.0f;
            float av[2][8];
            {
                const int d0c = ds0 + rotG * 8;
#pragma unroll
                for (int k = 0; k < 4; ++k) {
                    float2 v = ldA2(stream + HX(d0c + 2 * k, b2));
                    av[0][2 * k] = v.x; av[0][2 * k + 1] = v.y;
                }
            }
#pragma unroll
            for (int c = 0; c < 16; ++c) {
                const int cb = c & 1, pb = cb ^ 1;
                if (c < 15) {
                    const int dn = ds0 + ((c + 1 + rotG) & 15) * 8;
#pragma unroll
                    for (int k = 0; k < 4; ++k) {
                        float2 v = ldA2(stream + HX(dn + 2 * k, b2));
                        av[pb][2 * k] = v.x; av[pb][2 * k + 1] = v.y;
                    }
                }
                const int db = ds0 + ((c + rotG) & 15) * 8;
#pragma unroll
                for (int h2 = 0; h2 < 2; ++h2) {
                    const int q4 = (tb + db + h2 * 4) >> 2;
#pragma unroll
                    for (int r = 0; r < 12; ++r) {
                        float4 w = t4[(12 + r) * 256 + q4];
                        acc[r] = fmaf(w.x, av[cb][h2 * 4 + 0], acc[r]);
                        acc[r] = fmaf(w.y, av[cb][h2 * 4 + 1], acc[r]);
                        acc[r] = fmaf(w.z, av[cb][h2 * 4 + 2], acc[r]);
                        acc[r] = fmaf(w.w, av[cb][h2 * 4 + 3], acc[r]);
                    }
                }
            }
#pragma unroll
            for (int r = 0; r < 12; ++r) {
                int g = r >> 2;
                int prow = (g < 2) ? g * 4 : (iw ? 8 : 12);
                unsafeAtomicAdd(&smu[PR_OFF + (prow + (r & 3)) * 64 + lane], acc[r]);
            }
            __syncthreads();
            if (wv < 4) {
                int jl = wv, j = jg * 4 + jl;
                float* pr = smu + PR_OFF;
                float rs = pr[(0 + jl) * 64 + lane] + p.dbih1[j] + p.dbhh1[j];
                float zs = pr[(4 + jl) * 64 + lane] + p.dbih1[HH + j] + p.dbhh1[HH + j];
                float ins = pr[(8 + jl) * 64 + lane] + p.dbih1[2 * HH + j];
                float hns = pr[(12 + jl) * 64 + lane] + p.dbhh1[2 * HH + j];
                float r = sigf(rs), z = sigf(zs);
                float n = tanhf(ins + r * hns);
                float hp = ldA(h1s + HX(j, b2));
                stA(h1d + HX(j, b2), (1.0f - z) * n + z * hp);
            }
        }
        gbar(W, ++bar);

        // --- D: query + logits/argmax/tok ---
        {
            const int rotD = jg & 7;
            const float* h1c = h1d;
            if (tid < 256) smu[PR_OFF + tid] = 0.0f;
            __syncthreads();
            {
                const int ds0 = wv * 64;
                float acc4[4] = {0, 0, 0, 0};
                float av[2][8];
                {
                    const int d0c = ds0 + rotD * 8;
#pragma unroll
                    for (int k = 0; k < 4; ++k) {
                        float2 v = ldA2(h1c + HX(d0c + 2 * k, b2));
                        av[0][2 * k] = v.x; av[0][2 * k + 1] = v.y;
                    }
                }
#pragma unroll
                for (int c = 0; c < 8; ++c) {
                    const int cb = c & 1, pb = cb ^ 1;
                    if (c < 7) {
                        const int dn = ds0 + ((c + 1 + rotD) & 7) * 8;
#pragma unroll
                        for (int k = 0; k < 4; ++k) {
                            float2 v = ldA2(h1c + HX(dn + 2 * k, b2));
                            av[pb][2 * k] = v.x; av[pb][2 * k + 1] = v.y;
                        }
                    }
                    const int db = ds0 + ((c + rotD) & 7) * 8;
#pragma unroll
                    for (int h2 = 0; h2 < 2; ++h2) {
                        const int q4 = (db + h2 * 4) >> 2;
#pragma unroll
                        for (int jl = 0; jl < 4; ++jl) {
                            float4 w = t4q[jl * 128 + q4];
                            acc4[jl] = fmaf(w.x, av[cb][h2 * 4 + 0], acc4[jl]);
                            acc4[jl] = fmaf(w.y, av[cb][h2 * 4 + 1], acc4[jl]);
                            acc4[jl] = fmaf(w.z, av[cb][h2 * 4 + 2], acc4[jl]);
                            acc4[jl] = fmaf(w.w, av[cb][h2 * 4 + 3], acc4[jl]);
                        }
                    }
                }
#pragma unroll
                for (int jl = 0; jl < 4; ++jl)
                    unsafeAtomicAdd(&smu[PR_OFF + jl * 64 + lane], acc4[jl]);
            }
            __syncthreads();
            if (wv < 4) {
                int j = jg * 4 + wv;
                stA(qbm + HX(j, b2), smu[PR_OFF + wv * 64 + lane] + p.qb[j]);
            }
            if (blk >= 128 && blk < 160) {
                __syncthreads();
                const int bb = (blk - 128) * 4;
#pragma unroll
                for (int i = 0; i < 4; ++i) {
                    int f2 = i * 512 + tid;
                    int d = f2 >> 2, bi2 = f2 & 3;
                    smu[SC_OFF + f2] = ldA(h1c + HX(d, bb + bi2));
                }
                __syncthreads();
                if (tid < 128) {
                    const int bl = tid >> 5, v = tid & 31;
                    float acc = 0.0f;
                    for (int d4 = 0; d4 < 128; ++d4) {
                        float4 w4 = *(const float4*)(p.outW + (ll)v * HH + d4 * 4);
                        acc = fmaf(w4.x, smu[SC_OFF + (d4 * 4 + 0) * 4 + bl], acc);
                        acc = fmaf(w4.y, smu[SC_OFF + (d4 * 4 + 1) * 4 + bl], acc);
                        acc = fmaf(w4.z, smu[SC_OFF + (d4 * 4 + 2) * 4 + bl], acc);
                        acc = fmaf(w4.w, smu[SC_OFF + (d4 * 4 + 3) * 4 + bl], acc);
                    }
                    acc += p.outb[v];
                    p.vecO[((ll)(bb + bl) * MLEN + s) * VV + v] = acc;
                    smu[SC_OFF + 2048 + tid] = acc;
                }
                __syncthreads();
                if (tid < 4) {
                    int base = SC_OFF + 2048 + tid * 32;
                    float best = smu[base];
                    int bi2 = 0;
#pragma unroll
                    for (int u = 1; u < 32; ++u) {
                        float val = smu[base + u];
                        if (val > best) { best = val; bi2 = u; }
                    }
                    stAi(tok + bb + tid, bi2);
                }
            }
        }
        gbar(W, ++bar);
    }

    // ================= final hidden [2][128][512] =================
    {
        int idx = blk * 512 + tid;
        int l = idx >> 16, rr = idx & 65535;
        int b = rr >> 9, h = rr & 511;
        const float* src = l ? eh1 : (eh0 + SLOT);
        p.hidO[idx] = ldA(src + HX(h, b));
    }
}

extern "C" void kernel_launch(void* const* d_in, const int* in_sizes, int n_in,
                              void* d_out, int out_size, void* d_ws, size_t ws_size,
                              hipStream_t stream) {
    (void)in_sizes; (void)n_in; (void)out_size; (void)ws_size;
    P prm;
    prm.x     = (const float*)d_in[0];
    prm.emb   = (const float*)d_in[1];
    prm.eWih0 = (const float*)d_in[2];
    prm.eWhh0 = (const float*)d_in[3];
    prm.ebih0 = (const float*)d_in[4];
    prm.ebhh0 = (const float*)d_in[5];
    prm.eWih1 = (const float*)d_in[6];
    prm.eWhh1 = (const float*)d_in[7];
    prm.ebih1 = (const float*)d_in[8];
    prm.ebhh1 = (const float*)d_in[9];
    prm.dWih0 = (const float*)d_in[10];
    prm.dWhh0 = (const float*)d_in[11];
    prm.dbih0 = (const float*)d_in[12];
    prm.dbhh0 = (const float*)d_in[13];
    prm.dWih1 = (const float*)d_in[14];
    prm.dWhh1 = (const float*)d_in[15];
    prm.dbih1 = (const float*)d_in[16];
    prm.dbhh1 = (const float*)d_in[17];
    prm.qW    = (const float*)d_in[18];
    prm.qb    = (const float*)d_in[19];
    prm.outW  = (const float*)d_in[20];
    prm.outb  = (const float*)d_in[21];
    prm.ws    = (float*)d_ws;
    prm.vecO  = (float*)d_out;
    prm.hidO  = prm.vecO + (ll)BB * MLEN * VV;
    prm.attnO = prm.hidO + (ll)2 * BB * HH;

    hipMemsetAsync(d_ws, 0, 16384, stream);  // barrier gen + tree counters
    void* args[] = { &prm };
    hipLaunchCooperativeKernel((void*)kmain, dim3(256), dim3(512), args, 0, stream);
}

// Round 14
// 29440.018 us; speedup vs baseline: 2.1428x; 1.0002x over previous
//
#include <hip/hip_runtime.h>
#include <math.h>

#define BB 128
#define TT 256
#define HH 512
#define VV 32
#define MLEN 128
#define SLOT 65536          // HH*BB floats

// Static LDS layout (floats), 130048 bytes (R2-verified):
#define WT_OFF 0
#define QT_OFF 24576
#define PR_OFF 26624
#define SC_OFF 28416
#define SM_FLOATS 32512

// pair-packed layouts: element (d,b) of a [dim][128] buffer lives at
// (d/2)*256 + b*2 + (d&1)
#define HX(d, b) ((((d) >> 1) << 8) + ((b) << 1) + ((d) & 1))
#define SX(t, b) ((((t) >> 1) << 8) + ((b) << 1) + ((t) & 1))

typedef long long ll;

// PM-variant workspace extras (float offsets within f = ws+8192):
#define PM_OFF   17317888LL                    // Pm [256 t][512 d][128 b] pair-packed
#define QWT_OFF  (PM_OFF + 16777216LL)         // qW^T [512 d][512 j]
#define CT_OFF   (QWT_OFF + 262144LL)          // cT [256 t][128 b] pair-packed
#define WS_NEED  ((8192LL + CT_OFF + 32768LL) * 4)   // ~137.6 MB

struct P {
    const float *x, *emb;
    const float *eWih0, *eWhh0, *ebih0, *ebhh0;
    const float *eWih1, *eWhh1, *ebih1, *ebhh1;
    const float *dWih0, *dWhh0, *dbih0, *dbhh0;
    const float *dWih1, *dWhh1, *dbih1, *dbhh1;
    const float *qW, *qb, *outW, *outb;
    float *ws;
    float *vecO, *hidO, *attnO;
};

__device__ __forceinline__ float sigf(float v) { return 1.0f / (1.0f + __expf(-v)); }

__device__ __forceinline__ float ldA(const float* p) {
    return __hip_atomic_load(p, __ATOMIC_RELAXED, __HIP_MEMORY_SCOPE_AGENT);
}
__device__ __forceinline__ float2 ldA2(const float* p) {
    unsigned long long v = __hip_atomic_load((const unsigned long long*)p,
                                             __ATOMIC_RELAXED, __HIP_MEMORY_SCOPE_AGENT);
    union { unsigned long long u; float2 f; } c; c.u = v; return c.f;
}
__device__ __forceinline__ void stA(float* p, float v) {
    __hip_atomic_store(p, v, __ATOMIC_RELAXED, __HIP_MEMORY_SCOPE_AGENT);
}
__device__ __forceinline__ int ldAi(const int* p) {
    return __hip_atomic_load(p, __ATOMIC_RELAXED, __HIP_MEMORY_SCOPE_AGENT);
}
__device__ __forceinline__ void stAi(int* p, int v) {
    __hip_atomic_store(p, v, __ATOMIC_RELAXED, __HIP_MEMORY_SCOPE_AGENT);
}

__device__ __forceinline__ void gbar(int* W, int target) {
    __syncthreads();
    if (threadIdx.x == 0) {
        int par = target & 1;
        int g = blockIdx.x & 15;
        int* gc = W + 32 + (par * 16 + g) * 32;
        if (__hip_atomic_fetch_add(gc, 1, __ATOMIC_RELAXED, __HIP_MEMORY_SCOPE_AGENT) == 15) {
            __hip_atomic_store(gc, 0, __ATOMIC_RELAXED, __HIP_MEMORY_SCOPE_AGENT);
            int* rc = W + 1056 + par * 32;
            if (__hip_atomic_fetch_add(rc, 1, __ATOMIC_RELAXED, __HIP_MEMORY_SCOPE_AGENT) == 15) {
                __hip_atomic_store(rc, 0, __ATOMIC_RELAXED, __HIP_MEMORY_SCOPE_AGENT);
                __hip_atomic_store(W, target, __ATOMIC_RELAXED, __HIP_MEMORY_SCOPE_AGENT);
            }
        }
        while (__hip_atomic_load(W, __ATOMIC_RELAXED, __HIP_MEMORY_SCOPE_AGENT) < target)
            __builtin_amdgcn_s_sleep(2);
    }
    __syncthreads();
}

template<int PM>
__global__ __launch_bounds__(512, 1) void kmain(P p) {
    __shared__ __align__(16) float smu[SM_FLOATS];
    const int tid = threadIdx.x;
    const int lane = tid & 63;
    const int wv = tid >> 6;
    const int blk = blockIdx.x;

    int* W = (int*)p.ws;
    int* tok = W + 4096;
    float* f = (float*)p.ws + 8192;
    float* eh0 = f;
    float* eh1 = f + 2 * SLOT;
    float* inp = f + 4 * SLOT;
    float* qbm = f + 5 * SLOT;
    float* scoresB = f + 6 * SLOT;
    float* T = f + 6 * SLOT + SLOT / 2;
    float* xT = T + 3 * HH * VV;
    float* encO = f + (SLOT / 4) * 33;
    float* Pm  = f + PM_OFF;
    float* qWTp = f + QWT_OFF;
    float* cTp  = f + CT_OFF;

    const float4* t4 = (const float4*)smu;
    const float4* t4q = (const float4*)(smu + QT_OFF);

    const int jg = blk >> 1;
    const int bh = blk & 1;
    const int b2 = bh * 64 + lane;
    int bar = 0;

    // ================= INIT =================
    {
        stA(eh0 + blk * 1024 + tid, 0.0f);
        stA(eh0 + blk * 1024 + 512 + tid, 0.0f);
        if (tid < 256) {
            int idx = blk * 256 + tid;
            int t = idx >> 8, c = (idx >> 7) & 1, b = idx & 127;
            stA(xT + idx, p.x[((ll)b * TT + t) * 2 + c]);
        }
        if (tid < 192) {
            int unit = blk * 192 + tid;
            int v = unit & 31, gj = unit >> 5;
            const float* wrow = p.dWih0 + (ll)gj * 1024;
            const float* erow = p.emb + (ll)v * HH;
            float acc = 0.0f;
#pragma unroll 8
            for (int d = 0; d < HH; ++d) acc = fmaf(wrow[d], erow[d], acc);
            stA(T + unit, acc);
        }
        if constexpr (PM) {
            // qW^T build: qWT[d*512+j] = qW[j*512+d]
#pragma unroll
            for (int r = 0; r < 2; ++r) {
                int k = blk * 1024 + r * 512 + tid;
                int d = k >> 9, j = k & 511;
                stA(qWTp + k, p.qW[(ll)j * HH + d]);
            }
        }
#pragma unroll
        for (int jl = 0; jl < 4; ++jl)
            smu[QT_OFF + jl * 512 + tid] = p.qW[((ll)(jg * 4 + jl)) * HH + tid];
#pragma unroll
        for (int r = 0; r < 24; ++r) {
            int g = r >> 2, jl = r & 3, j = jg * 4 + jl;
            const float* src = (g < 3) ? (p.eWhh0 + (ll)(g * HH + j) * HH)
                                       : (p.eWih1 + (ll)((g - 3) * HH + j) * HH);
            smu[WT_OFF + r * 512 + tid] = src[tid];
        }
#pragma unroll
        for (int r = 0; r < 12; ++r) {
            int g = r >> 2, jl = r & 3, j = jg * 4 + jl;
            smu[WT_OFF + (24 + r) * 512 + tid] = p.eWhh1[(ll)(g * HH + j) * HH + tid];
        }
        gbar(W, ++bar);
    }

    // ================= ENCODER =================
    for (int t = 0; t <= TT; ++t) {
        const float* h0s = eh0 + (((t + 1) & 1) ? SLOT : 0);
        float*       h0d = eh0 + ((t & 1) ? SLOT : 0);
        const float* h1s = eh1 + (((t + 1) & 1) ? SLOT : 0);
        float*       h1d = eh1 + ((t & 1) ? SLOT : 0);

        smu[PR_OFF + tid] = 0.0f;
        smu[PR_OFF + 512 + tid] = 0.0f;
        smu[PR_OFF + 1024 + tid] = 0.0f;
        if (tid < 256) smu[PR_OFF + 1536 + tid] = 0.0f;
        __syncthreads();

        {
            const int rotE = jg & 7;
            const int ds0 = wv * 64;
            float acc[36];
#pragma unroll
            for (int r = 0; r < 36; ++r) acc[r] = 0.0f;
            float av[2][8], bv[2][8];
            {
                const int d0c = ds0 + rotE * 8;
#pragma unroll
                for (int k = 0; k < 4; ++k) {
                    float2 va = ldA2(h0s + HX(d0c + 2 * k, b2));
                    av[0][2 * k] = va.x; av[0][2 * k + 1] = va.y;
                    float2 vb = ldA2(h1s + HX(d0c + 2 * k, b2));
                    bv[0][2 * k] = vb.x; bv[0][2 * k + 1] = vb.y;
                }
            }
#pragma unroll
            for (int c = 0; c < 8; ++c) {
                const int cb = c & 1, pb = cb ^ 1;
                if (c < 7) {
                    const int dn = ds0 + ((c + 1 + rotE) & 7) * 8;
#pragma unroll
                    for (int k = 0; k < 4; ++k) {
                        float2 va = ldA2(h0s + HX(dn + 2 * k, b2));
                        av[pb][2 * k] = va.x; av[pb][2 * k + 1] = va.y;
                        float2 vb = ldA2(h1s + HX(dn + 2 * k, b2));
                        bv[pb][2 * k] = vb.x; bv[pb][2 * k + 1] = vb.y;
                    }
                }
                const int db = ds0 + ((c + rotE) & 7) * 8;
#pragma unroll
                for (int h2 = 0; h2 < 2; ++h2) {
                    const int q4 = (db + h2 * 4) >> 2;
#pragma unroll
                    for (int r = 0; r < 24; ++r) {
                        float4 w = t4[r * 128 + q4];
                        acc[r] = fmaf(w.x, av[cb][h2 * 4 + 0], acc[r]);
                        acc[r] = fmaf(w.y, av[cb][h2 * 4 + 1], acc[r]);
                        acc[r] = fmaf(w.z, av[cb][h2 * 4 + 2], acc[r]);
                        acc[r] = fmaf(w.w, av[cb][h2 * 4 + 3], acc[r]);
                    }
#pragma unroll
                    for (int r = 0; r < 12; ++r) {
                        float4 w = t4[(24 + r) * 128 + q4];
                        acc[24 + r] = fmaf(w.x, bv[cb][h2 * 4 + 0], acc[24 + r]);
                        acc[24 + r] = fmaf(w.y, bv[cb][h2 * 4 + 1], acc[24 + r]);
                        acc[24 + r] = fmaf(w.z, bv[cb][h2 * 4 + 2], acc[24 + r]);
                        acc[24 + r] = fmaf(w.w, bv[cb][h2 * 4 + 3], acc[24 + r]);
                    }
                }
            }
#pragma unroll
            for (int r = 0; r < 24; ++r)
                unsafeAtomicAdd(&smu[PR_OFF + r * 64 + lane], acc[r]);
#pragma unroll
            for (int r = 0; r < 12; ++r) {
                int g = r >> 2;
                int prow = (g < 2) ? (12 + g * 4) : 24;
                unsafeAtomicAdd(&smu[PR_OFF + (prow + (r & 3)) * 64 + lane], acc[24 + r]);
            }
        }
        __syncthreads();

        if (wv < 4) {
            if (t < TT) {
                int jl = wv, j = jg * 4 + jl;
                float* pr = smu + PR_OFF;
                float hr = pr[(0 + jl) * 64 + lane] + p.ebhh0[j];
                float hz = pr[(4 + jl) * 64 + lane] + p.ebhh0[HH + j];
                float hn = pr[(8 + jl) * 64 + lane] + p.ebhh0[2 * HH + j];
                float x0 = xT[t * 256 + b2], x1 = xT[t * 256 + 128 + b2];
                float ir = fmaf(p.eWih0[j * 2], x0, fmaf(p.eWih0[j * 2 + 1], x1, p.ebih0[j]));
                float iz = fmaf(p.eWih0[(HH + j) * 2], x0, fmaf(p.eWih0[(HH + j) * 2 + 1], x1, p.ebih0[HH + j]));
                float in_ = fmaf(p.eWih0[(2 * HH + j) * 2], x0, fmaf(p.eWih0[(2 * HH + j) * 2 + 1], x1, p.ebih0[2 * HH + j]));
                float r = sigf(ir + hr), z = sigf(iz + hz);
                float n = tanhf(in_ + r * hn);
                float hp = ldA(h0s + HX(j, b2));
                stA(h0d + HX(j, b2), (1.0f - z) * n + z * hp);
            }
        } else if (t >= 1) {
            int jl = wv - 4, j = jg * 4 + jl;
            float* pr = smu + PR_OFF;
            float rs = pr[(12 + jl) * 64 + lane] + p.ebih1[j] + p.ebhh1[j];
            float zs = pr[(16 + jl) * 64 + lane] + p.ebih1[HH + j] + p.ebhh1[HH + j];
            float in1 = pr[(20 + jl) * 64 + lane] + p.ebih1[2 * HH + j];
            float hn1 = pr[(24 + jl) * 64 + lane] + p.ebhh1[2 * HH + j];
            float r = sigf(rs), z = sigf(zs);
            float n = tanhf(in1 + r * hn1);
            float hp = ldA(h1s + HX(j, b2));
            float hv = (1.0f - z) * n + z * hp;
            stA(h1d + HX(j, b2), hv);
            stA(encO + (ll)(t - 1) * (HH * BB) + HX(j, b2), hv);
        }
        gbar(W, ++bar);
    }

    // ================= DEC-INIT =================
    {
        if (tid < 256) smu[PR_OFF + tid] = 0.0f;
#pragma unroll
        for (int r = 0; r < 12; ++r) {
            int g = r >> 2, jl = r & 3, j = jg * 4 + jl;
            smu[WT_OFF + r * 1024 + tid]              = p.dWih0[(ll)(g * HH + j) * 1024 + 512 + tid];
            smu[WT_OFF + r * 1024 + 512 + tid]        = p.dWhh0[(ll)(g * HH + j) * HH + tid];
            smu[WT_OFF + (12 + r) * 1024 + tid]       = p.dWih1[(ll)(g * HH + j) * HH + tid];
            smu[WT_OFF + (12 + r) * 1024 + 512 + tid] = p.dWhh1[(ll)(g * HH + j) * HH + tid];
        }
        __syncthreads();
        if constexpr (!PM) {
            const float* h1c = eh1;  // slot 0
            const int ds0 = wv * 64;
            float acc[4] = {0, 0, 0, 0};
            float av[8];
            for (int c = 0; c < 8; ++c) {
                int db = ds0 + c * 8;
#pragma unroll
                for (int k = 0; k < 4; ++k) {
                    float2 v = ldA2(h1c + HX(db + 2 * k, b2));
                    av[2 * k] = v.x; av[2 * k + 1] = v.y;
                }
#pragma unroll
                for (int h2 = 0; h2 < 2; ++h2) {
                    int q4 = (db + h2 * 4) >> 2;
#pragma unroll
                    for (int jl = 0; jl < 4; ++jl) {
                        float4 w = t4q[jl * 128 + q4];
                        acc[jl] = fmaf(w.x, av[h2 * 4 + 0], acc[jl]);
                        acc[jl] = fmaf(w.y, av[h2 * 4 + 1], acc[jl]);
                        acc[jl] = fmaf(w.z, av[h2 * 4 + 2], acc[jl]);
                        acc[jl] = fmaf(w.w, av[h2 * 4 + 3], acc[jl]);
                    }
                }
            }
#pragma unroll
            for (int jl = 0; jl < 4; ++jl)
                unsafeAtomicAdd(&smu[PR_OFF + jl * 64 + lane], acc[jl]);
            __syncthreads();
            if (wv < 4) {
                int j = jg * 4 + wv;
                stA(qbm + HX(j, b2), smu[PR_OFF + wv * 64 + lane] + p.qb[j]);
            }
        } else {
            // Pm[t][d][b] = sum_j qW[j][d]*encO[t][j][b]; cT[t][b] = sum_j qb[j]*encO[t][j][b]
            const int t0p = (blk >> 1) * 2;
#pragma unroll 1
            for (int tt = 0; tt < 2; ++tt) {
                const int t = t0p + tt;
                const float* Eb = encO + (ll)t * (HH * BB) + (b2 << 1);
                float* Pb = Pm + (ll)t * (HH * BB);
#pragma unroll 1
                for (int dc = 0; dc < 8; ++dc) {
                    const int dbase = wv * 64 + dc * 8;
                    float acc8[8];
#pragma unroll
                    for (int u = 0; u < 8; ++u) acc8[u] = 0.0f;
                    const float2* q0 = (const float2*)(qWTp + (ll)(dbase + 0) * HH);
                    const float2* q1 = (const float2*)(qWTp + (ll)(dbase + 1) * HH);
                    const float2* q2p = (const float2*)(qWTp + (ll)(dbase + 2) * HH);
                    const float2* q3 = (const float2*)(qWTp + (ll)(dbase + 3) * HH);
                    const float2* q4p = (const float2*)(qWTp + (ll)(dbase + 4) * HH);
                    const float2* q5 = (const float2*)(qWTp + (ll)(dbase + 5) * HH);
                    const float2* q6 = (const float2*)(qWTp + (ll)(dbase + 6) * HH);
                    const float2* q7 = (const float2*)(qWTp + (ll)(dbase + 7) * HH);
#pragma unroll 4
                    for (int jp = 0; jp < 256; ++jp) {
                        float2 e2 = *(const float2*)(Eb + (jp << 8));
                        float2 w;
                        w = q0[jp]; acc8[0] = fmaf(w.x, e2.x, fmaf(w.y, e2.y, acc8[0]));
                        w = q1[jp]; acc8[1] = fmaf(w.x, e2.x, fmaf(w.y, e2.y, acc8[1]));
                        w = q2p[jp]; acc8[2] = fmaf(w.x, e2.x, fmaf(w.y, e2.y, acc8[2]));
                        w = q3[jp]; acc8[3] = fmaf(w.x, e2.x, fmaf(w.y, e2.y, acc8[3]));
                        w = q4p[jp]; acc8[4] = fmaf(w.x, e2.x, fmaf(w.y, e2.y, acc8[4]));
                        w = q5[jp]; acc8[5] = fmaf(w.x, e2.x, fmaf(w.y, e2.y, acc8[5]));
                        w = q6[jp]; acc8[6] = fmaf(w.x, e2.x, fmaf(w.y, e2.y, acc8[6]));
                        w = q7[jp]; acc8[7] = fmaf(w.x, e2.x, fmaf(w.y, e2.y, acc8[7]));
                    }
#pragma unroll
                    for (int u = 0; u < 8; ++u) {
                        int d = dbase + u;
                        stA(Pb + HX(d, b2), acc8[u]);
                    }
                }
            }
            if (wv == 0) {
#pragma unroll 1
                for (int tt = 0; tt < 2; ++tt) {
                    const int t = t0p + tt;
                    const float* Eb = encO + (ll)t * (HH * BB) + (b2 << 1);
                    float acc = 0.0f;
#pragma unroll 4
                    for (int jp = 0; jp < 256; ++jp) {
                        float2 e2 = *(const float2*)(Eb + (jp << 8));
                        float2 qv2 = *(const float2*)(p.qb + jp * 2);
                        acc = fmaf(qv2.x, e2.x, fmaf(qv2.y, e2.y, acc));
                    }
                    stA(cTp + SX(t, b2), acc);
                }
            }
        }
        if (blk == 128 && tid < BB) stAi(tok + tid, 0);
        gbar(W, ++bar);
    }

    // ================= DECODER =================
    for (int s = 0; s < MLEN; ++s) {
        const float* h0s = eh0 + (((s + 1) & 1) ? SLOT : 0);
        float*       g0d = eh0 + ((s & 1) ? SLOT : 0);
        const float* h1s = eh1 + ((s & 1) ? SLOT : 0);
        float*       h1d = eh1 + (((s + 1) & 1) ? SLOT : 0);

        // --- A1: scores (+ merged logits for PM) ---
        {
            const int rotA = jg & 7;
            const int t0 = (blk >> 1) * 2;
            if (tid < 128) smu[PR_OFF + tid] = 0.0f;
            __syncthreads();
            const int js = wv * 64;
            float a0 = 0.0f, a1 = 0.0f;
            float qv[2][8], e0[2][8], e1[2][8];
            const float* S0 = PM ? (Pm + (ll)t0 * (HH * BB)) : (encO + (ll)t0 * (HH * BB));
            const float* S1 = PM ? (Pm + (ll)(t0 + 1) * (HH * BB)) : (encO + (ll)(t0 + 1) * (HH * BB));
            const float* Qs = PM ? h1s : qbm;
            {
                const int j0 = js + rotA * 8;
                const float* eb0 = S0 + ((j0 >> 1) << 8) + (b2 << 1);
                const float* eb1 = S1 + ((j0 >> 1) << 8) + (b2 << 1);
#pragma unroll
                for (int k = 0; k < 4; ++k) {
                    float2 q2 = ldA2(Qs + HX(j0 + 2 * k, b2));
                    qv[0][2 * k] = q2.x; qv[0][2 * k + 1] = q2.y;
                    float2 v0 = *(const float2*)(eb0 + k * 256);
                    e0[0][2 * k] = v0.x; e0[0][2 * k + 1] = v0.y;
                    float2 v1 = *(const float2*)(eb1 + k * 256);
                    e1[0][2 * k] = v1.x; e1[0][2 * k + 1] = v1.y;
                }
            }
#pragma unroll
            for (int c = 0; c < 8; ++c) {
                const int cb = c & 1, pb = cb ^ 1;
                if (c < 7) {
                    const int jn = js + ((c + 1 + rotA) & 7) * 8;
                    const float* eb0 = S0 + ((jn >> 1) << 8) + (b2 << 1);
                    const float* eb1 = S1 + ((jn >> 1) << 8) + (b2 << 1);
#pragma unroll
                    for (int k = 0; k < 4; ++k) {
                        float2 q2 = ldA2(Qs + HX(jn + 2 * k, b2));
                        qv[pb][2 * k] = q2.x; qv[pb][2 * k + 1] = q2.y;
                        float2 v0 = *(const float2*)(eb0 + k * 256);
                        e0[pb][2 * k] = v0.x; e0[pb][2 * k + 1] = v0.y;
                        float2 v1 = *(const float2*)(eb1 + k * 256);
                        e1[pb][2 * k] = v1.x; e1[pb][2 * k + 1] = v1.y;
                    }
                }
#pragma unroll
                for (int u = 0; u < 8; ++u) {
                    a0 = fmaf(qv[cb][u], e0[cb][u], a0);
                    a1 = fmaf(qv[cb][u], e1[cb][u], a1);
                }
            }
            unsafeAtomicAdd(&smu[PR_OFF + lane], a0);
            unsafeAtomicAdd(&smu[PR_OFF + 64 + lane], a1);
            __syncthreads();
            if (wv < 2) {
                float base = smu[PR_OFF + wv * 64 + lane];
                if constexpr (PM) base += cTp[SX(t0 + wv, b2)];
                stA(scoresB + SX(t0 + wv, b2), base);
            }
            if constexpr (PM) {
                if (blk >= 128 && blk < 160 && s >= 1) {
                    __syncthreads();
                    const int bb = (blk - 128) * 4;
#pragma unroll
                    for (int i = 0; i < 4; ++i) {
                        int f2 = i * 512 + tid;
                        int d = f2 >> 2, bi2 = f2 & 3;
                        smu[SC_OFF + f2] = ldA(h1s + HX(d, bb + bi2));
                    }
                    __syncthreads();
                    if (tid < 128) {
                        const int bl = tid >> 5, v = tid & 31;
                        float acc = 0.0f;
                        for (int d4 = 0; d4 < 128; ++d4) {
                            float4 w4 = *(const float4*)(p.outW + (ll)v * HH + d4 * 4);
                            acc = fmaf(w4.x, smu[SC_OFF + (d4 * 4 + 0) * 4 + bl], acc);
                            acc = fmaf(w4.y, smu[SC_OFF + (d4 * 4 + 1) * 4 + bl], acc);
                            acc = fmaf(w4.z, smu[SC_OFF + (d4 * 4 + 2) * 4 + bl], acc);
                            acc = fmaf(w4.w, smu[SC_OFF + (d4 * 4 + 3) * 4 + bl], acc);
                        }
                        acc += p.outb[v];
                        p.vecO[((ll)(bb + bl) * MLEN + (s - 1)) * VV + v] = acc;
                        smu[SC_OFF + 2048 + tid] = acc;
                    }
                    __syncthreads();
                    if (tid < 4) {
                        int base = SC_OFF + 2048 + tid * 32;
                        float best = smu[base];
                        int bi2 = 0;
#pragma unroll
                        for (int u = 1; u < 32; ++u) {
                            float val = smu[base + u];
                            if (val > best) { best = val; bi2 = u; }
                        }
                        stAi(tok + bb + tid, bi2);
                    }
                }
            }
        }
        gbar(W, ++bar);

        // --- A2: softmax + context ---
        {
            const int d0 = jg * 4;
            float sv[32];
#pragma unroll
            for (int kp = 0; kp < 16; ++kp) {
                float2 v = ldA2(scoresB + ((wv * 16 + kp) << 8) + (b2 << 1));
                sv[2 * kp] = v.x; sv[2 * kp + 1] = v.y;
            }
            if (tid < 256) smu[PR_OFF + tid] = 0.0f;
            float mp = sv[0];
#pragma unroll
            for (int k = 1; k < 32; ++k) mp = fmaxf(mp, sv[k]);
            smu[SC_OFF + wv * 64 + lane] = mp;
            __syncthreads();
            float m = smu[SC_OFF + lane];
#pragma unroll
            for (int u = 1; u < 8; ++u) m = fmaxf(m, smu[SC_OFF + u * 64 + lane]);
            float e[32], lp = 0.0f;
#pragma unroll
            for (int k = 0; k < 32; ++k) { e[k] = __expf(sv[k] - m); lp += e[k]; }
            smu[SC_OFF + 512 + wv * 64 + lane] = lp;
            __syncthreads();
            float l = smu[SC_OFF + 512 + lane];
#pragma unroll
            for (int u = 1; u < 8; ++u) l += smu[SC_OFF + 512 + u * 64 + lane];
            float rl = 1.0f / l;
            if (blk < 16 && wv == jg) {
#pragma unroll
                for (int k = 0; k < 32; ++k) smu[SC_OFF + 1024 + k * 65 + lane] = e[k] * rl;
            }
            float c4[4] = {0, 0, 0, 0};
            float ev[2][32];
#pragma unroll
            for (int u = 0; u < 8; ++u) {
                const float* Ep = encO + (ll)(wv * 32 + u) * (HH * BB) + ((d0 >> 1) << 8) + (b2 << 1);
                float2 pa = *(const float2*)(Ep);
                float2 pb2 = *(const float2*)(Ep + 256);
                ev[0][u * 4 + 0] = pa.x; ev[0][u * 4 + 1] = pa.y;
                ev[0][u * 4 + 2] = pb2.x; ev[0][u * 4 + 3] = pb2.y;
            }
#pragma unroll
            for (int kb = 0; kb < 4; ++kb) {
                const int cb = kb & 1, pb = cb ^ 1;
                if (kb < 3) {
#pragma unroll
                    for (int u = 0; u < 8; ++u) {
                        const float* Ep = encO + (ll)(wv * 32 + (kb + 1) * 8 + u) * (HH * BB) + ((d0 >> 1) << 8) + (b2 << 1);
                        float2 pa = *(const float2*)(Ep);
                        float2 pb2 = *(const float2*)(Ep + 256);
                        ev[pb][u * 4 + 0] = pa.x; ev[pb][u * 4 + 1] = pa.y;
                        ev[pb][u * 4 + 2] = pb2.x; ev[pb][u * 4 + 3] = pb2.y;
                    }
                }
#pragma unroll
                for (int u = 0; u < 8; ++u) {
                    const int k = kb * 8 + u;
                    c4[0] = fmaf(e[k], ev[cb][u * 4 + 0], c4[0]);
                    c4[1] = fmaf(e[k], ev[cb][u * 4 + 1], c4[1]);
                    c4[2] = fmaf(e[k], ev[cb][u * 4 + 2], c4[2]);
                    c4[3] = fmaf(e[k], ev[cb][u * 4 + 3], c4[3]);
                }
            }
#pragma unroll
            for (int kk = 0; kk < 4; ++kk)
                unsafeAtomicAdd(&smu[PR_OFF + kk * 64 + lane], c4[kk]);
            __syncthreads();
            if (tid < 256) {
                int kk = tid >> 6, ln = tid & 63;
                float l2 = smu[SC_OFF + 512 + ln];
#pragma unroll
                for (int u = 1; u < 8; ++u) l2 += smu[SC_OFF + 512 + u * 64 + ln];
                float val = smu[PR_OFF + kk * 64 + ln] / l2;
                stA(inp + HX(d0 + kk, bh * 64 + ln), val);
            }
            if (blk < 16) {
                int bi = tid >> 3, tj = tid & 7;
#pragma unroll
                for (int u = 0; u < 4; ++u) {
                    int tl = tj * 4 + u;
                    p.attnO[((ll)(bh * 64 + bi) * MLEN + s) * TT + jg * 32 + tl] = smu[SC_OFF + 1024 + tl * 65 + bi];
                }
            }
        }
        gbar(W, ++bar);

        // --- G0 ---
        {
            const int rotG = jg & 15;
            smu[PR_OFF + tid] = 0.0f;
            smu[PR_OFF + 512 + tid] = 0.0f;
            __syncthreads();
            const int ctxw = (wv < 4);
            const float* stream = ctxw ? inp : h0s;
            const int ds0 = (wv & 3) * 128;
            const int tb = ctxw ? 0 : 512;
            float acc[12];
#pragma unroll
            for (int r = 0; r < 12; ++r) acc[r] = 0.0f;
            float av[2][8];
            {
                const int d0c = ds0 + rotG * 8;
#pragma unroll
                for (int k = 0; k < 4; ++k) {
                    float2 v = ldA2(stream + HX(d0c + 2 * k, b2));
                    av[0][2 * k] = v.x; av[0][2 * k + 1] = v.y;
                }
            }
#pragma unroll
            for (int c = 0; c < 16; ++c) {
                const int cb = c & 1, pb = cb ^ 1;
                if (c < 15) {
                    const int dn = ds0 + ((c + 1 + rotG) & 15) * 8;
#pragma unroll
                    for (int k = 0; k < 4; ++k) {
                        float2 v = ldA2(stream + HX(dn + 2 * k, b2));
                        av[pb][2 * k] = v.x; av[pb][2 * k + 1] = v.y;
                    }
                }
                const int db = ds0 + ((c + rotG) & 15) * 8;
#pragma unroll
                for (int h2 = 0; h2 < 2; ++h2) {
                    const int q4 = (tb + db + h2 * 4) >> 2;
#pragma unroll
                    for (int r = 0; r < 12; ++r) {
                        float4 w = t4[r * 256 + q4];
                        acc[r] = fmaf(w.x, av[cb][h2 * 4 + 0], acc[r]);
                        acc[r] = fmaf(w.y, av[cb][h2 * 4 + 1], acc[r]);
                        acc[r] = fmaf(w.z, av[cb][h2 * 4 + 2], acc[r]);
                        acc[r] = fmaf(w.w, av[cb][h2 * 4 + 3], acc[r]);
                    }
                }
            }
#pragma unroll
            for (int r = 0; r < 12; ++r) {
                int g = r >> 2;
                int prow = (g < 2) ? g * 4 : (ctxw ? 8 : 12);
                unsafeAtomicAdd(&smu[PR_OFF + (prow + (r & 3)) * 64 + lane], acc[r]);
            }
            __syncthreads();
            if (wv < 4) {
                int jl = wv, j = jg * 4 + jl;
                float* pr = smu + PR_OFF;
                int tokb = ldAi(tok + b2);
                float rs = T[(ll)j * 32 + tokb] + pr[(0 + jl) * 64 + lane] + p.dbih0[j] + p.dbhh0[j];
                float zs = T[(ll)(HH + j) * 32 + tokb] + pr[(4 + jl) * 64 + lane] + p.dbih0[HH + j] + p.dbhh0[HH + j];
                float ins = T[(ll)(2 * HH + j) * 32 + tokb] + pr[(8 + jl) * 64 + lane] + p.dbih0[2 * HH + j];
                float hns = pr[(12 + jl) * 64 + lane] + p.dbhh0[2 * HH + j];
                float r = sigf(rs), z = sigf(zs);
                float n = tanhf(ins + r * hns);
                float hp = ldA(h0s + HX(j, b2));
                stA(g0d + HX(j, b2), (1.0f - z) * n + z * hp);
            }
        }
        gbar(W, ++bar);

        // --- G1 ---
        {
            const int rotG = jg & 15;
            smu[PR_OFF + tid] = 0.0f;
            smu[PR_OFF + 512 + tid] = 0.0f;
            __syncthreads();
            const int iw = (wv < 4);
            const float* stream = iw ? g0d : h1s;
            const int ds0 = (wv & 3) * 128;
            const int tb = iw ? 0 : 512;
            float acc[12];
#pragma unroll
            for (int r = 0; r < 12; ++r) acc[r] = 0.0f;
            float av[2][8];
            {
                const int d0c = ds0 + rotG * 8;
#pragma unroll
                for (int k = 0; k < 4; ++k) {
                    float2 v = ldA2(stream + HX(d0c + 2 * k, b2));
                    av[0][2 * k] = v.x; av[0][2 * k + 1] = v.y;
                }
            }
#pragma unroll
            for (int c = 0; c < 16; ++c) {
                const int cb = c & 1, pb = cb ^ 1;
                if (c < 15) {
                    const int dn = ds0 + ((c + 1 + rotG) & 15) * 8;
#pragma unroll
                    for (int k = 0; k < 4; ++k) {
                        float2 v = ldA2(stream + HX(dn + 2 * k, b2));
                        av[pb][2 * k] = v.x; av[pb][2 * k + 1] = v.y;
                    }
                }
                const int db = ds0 + ((c + rotG) & 15) * 8;
#pragma unroll
                for (int h2 = 0; h2 < 2; ++h2) {
                    const int q4 = (tb + db + h2 * 4) >> 2;
#pragma unroll
                    for (int r = 0; r < 12; ++r) {
                        float4 w = t4[(12 + r) * 256 + q4];
                        acc[r] = fmaf(w.x, av[cb][h2 * 4 + 0], acc[r]);
                        acc[r] = fmaf(w.y, av[cb][h2 * 4 + 1], acc[r]);
                        acc[r] = fmaf(w.z, av[cb][h2 * 4 + 2], acc[r]);
                        acc[r] = fmaf(w.w, av[cb][h2 * 4 + 3], acc[r]);
                    }
                }
            }
#pragma unroll
            for (int r = 0; r < 12; ++r) {
                int g = r >> 2;
                int prow = (g < 2) ? g * 4 : (iw ? 8 : 12);
                unsafeAtomicAdd(&smu[PR_OFF + (prow + (r & 3)) * 64 + lane], acc[r]);
            }
            __syncthreads();
            if (wv < 4) {
                int jl = wv, j = jg * 4 + jl;
                float* pr = smu + PR_OFF;
                float rs = pr[(0 + jl) * 64 + lane] + p.dbih1[j] + p.dbhh1[j];
                float zs = pr[(4 + jl) * 64 + lane] + p.dbih1[HH + j] + p.dbhh1[HH + j];
                float ins = pr[(8 + jl) * 64 + lane] + p.dbih1[2 * HH + j];
                float hns = pr[(12 + jl) * 64 + lane] + p.dbhh1[2 * HH + j];
                float r = sigf(rs), z = sigf(zs);
                float n = tanhf(ins + r * hns);
                float hp = ldA(h1s + HX(j, b2));
                stA(h1d + HX(j, b2), (1.0f - z) * n + z * hp);
            }
        }
        gbar(W, ++bar);

        // --- D (PM=0 only): query + logits/argmax ---
        if constexpr (!PM) {
            const int rotD = jg & 7;
            const float* h1c = h1d;
            if (tid < 256) smu[PR_OFF + tid] = 0.0f;
            __syncthreads();
            {
                const int ds0 = wv * 64;
                float acc4[4] = {0, 0, 0, 0};
                float av[2][8];
                {
                    const int d0c = ds0 + rotD * 8;
#pragma unroll
                    for (int k = 0; k < 4; ++k) {
                        float2 v = ldA2(h1c + HX(d0c + 2 * k, b2));
                        av[0][2 * k] = v.x; av[0][2 * k + 1] = v.y;
                    }
                }
#pragma unroll
                for (int c = 0; c < 8; ++c) {
                    const int cb = c & 1, pb = cb ^ 1;
                    if (c < 7) {
                        const int dn = ds0 + ((c + 1 + rotD) & 7) * 8;
#pragma unroll
                        for (int k = 0; k < 4; ++k) {
                            float2 v = ldA2(h1c + HX(dn + 2 * k, b2));
                            av[pb][2 * k] = v.x; av[pb][2 * k + 1] = v.y;
                        }
                    }
                    const int db = ds0 + ((c + rotD) & 7) * 8;
#pragma unroll
                    for (int h2 = 0; h2 < 2; ++h2) {
                        const int q4 = (db + h2 * 4) >> 2;
#pragma unroll
                        for (int jl = 0; jl < 4; ++jl) {
                            float4 w = t4q[jl * 128 + q4];
                            acc4[jl] = fmaf(w.x, av[cb][h2 * 4 + 0], acc4[jl]);
                            acc4[jl] = fmaf(w.y, av[cb][h2 * 4 + 1], acc4[jl]);
                            acc4[jl] = fmaf(w.z, av[cb][h2 * 4 + 2], acc4[jl]);
                            acc4[jl] = fmaf(w.w, av[cb][h2 * 4 + 3], acc4[jl]);
                        }
                    }
                }
#pragma unroll
                for (int jl = 0; jl < 4; ++jl)
                    unsafeAtomicAdd(&smu[PR_OFF + jl * 64 + lane], acc4[jl]);
            }
            __syncthreads();
            if (wv < 4) {
                int j = jg * 4 + wv;
                stA(qbm + HX(j, b2), smu[PR_OFF + wv * 64 + lane] + p.qb[j]);
            }
            if (blk >= 128 && blk < 160) {
                __syncthreads();
                const int bb = (blk - 128) * 4;
#pragma unroll
                for (int i = 0; i < 4; ++i) {
                    int f2 = i * 512 + tid;
                    int d = f2 >> 2, bi2 = f2 & 3;
                    smu[SC_OFF + f2] = ldA(h1c + HX(d, bb + bi2));
                }
                __syncthreads();
                if (tid < 128) {
                    const int bl = tid >> 5, v = tid & 31;
                    float acc = 0.0f;
                    for (int d4 = 0; d4 < 128; ++d4) {
                        float4 w4 = *(const float4*)(p.outW + (ll)v * HH + d4 * 4);
                        acc = fmaf(w4.x, smu[SC_OFF + (d4 * 4 + 0) * 4 + bl], acc);
                        acc = fmaf(w4.y, smu[SC_OFF + (d4 * 4 + 1) * 4 + bl], acc);
                        acc = fmaf(w4.z, smu[SC_OFF + (d4 * 4 + 2) * 4 + bl], acc);
                        acc = fmaf(w4.w, smu[SC_OFF + (d4 * 4 + 3) * 4 + bl], acc);
                    }
                    acc += p.outb[v];
                    p.vecO[((ll)(bb + bl) * MLEN + s) * VV + v] = acc;
                    smu[SC_OFF + 2048 + tid] = acc;
                }
                __syncthreads();
                if (tid < 4) {
                    int base = SC_OFF + 2048 + tid * 32;
                    float best = smu[base];
                    int bi2 = 0;
#pragma unroll
                    for (int u = 1; u < 32; ++u) {
                        float val = smu[base + u];
                        if (val > best) { best = val; bi2 = u; }
                    }
                    stAi(tok + bb + tid, bi2);
                }
            }
            gbar(W, ++bar);
        }
    }

    // ================= PM epilogue: logits for s = 127 =================
    if constexpr (PM) {
        if (blk >= 128 && blk < 160) {
            const float* h1c = eh1;   // slot 0 = h1 after step 127
            const int bb = (blk - 128) * 4;
            __syncthreads();
#pragma unroll
            for (int i = 0; i < 4; ++i) {
                int f2 = i * 512 + tid;
                int d = f2 >> 2, bi2 = f2 & 3;
                smu[SC_OFF + f2] = ldA(h1c + HX(d, bb + bi2));
            }
            __syncthreads();
            if (tid < 128) {
                const int bl = tid >> 5, v = tid & 31;
                float acc = 0.0f;
                for (int d4 = 0; d4 < 128; ++d4) {
                    float4 w4 = *(const float4*)(p.outW + (ll)v * HH + d4 * 4);
                    acc = fmaf(w4.x, smu[SC_OFF + (d4 * 4 + 0) * 4 + bl], acc);
                    acc = fmaf(w4.y, smu[SC_OFF + (d4 * 4 + 1) * 4 + bl], acc);
                    acc = fmaf(w4.z, smu[SC_OFF + (d4 * 4 + 2) * 4 + bl], acc);
                    acc = fmaf(w4.w, smu[SC_OFF + (d4 * 4 + 3) * 4 + bl], acc);
                }
                acc += p.outb[v];
                p.vecO[((ll)(bb + bl) * MLEN + (MLEN - 1)) * VV + v] = acc;
            }
        }
    }

    // ================= final hidden [2][128][512] =================
    {
        int idx = blk * 512 + tid;
        int l = idx >> 16, rr = idx & 65535;
        int b = rr >> 9, h = rr & 511;
        const float* src = l ? eh1 : (eh0 + SLOT);
        p.hidO[idx] = ldA(src + HX(h, b));
    }
}

extern "C" void kernel_launch(void* const* d_in, const int* in_sizes, int n_in,
                              void* d_out, int out_size, void* d_ws, size_t ws_size,
                              hipStream_t stream) {
    (void)in_sizes; (void)n_in; (void)out_size;
    P prm;
    prm.x     = (const float*)d_in[0];
    prm.emb   = (const float*)d_in[1];
    prm.eWih0 = (const float*)d_in[2];
    prm.eWhh0 = (const float*)d_in[3];
    prm.ebih0 = (const float*)d_in[4];
    prm.ebhh0 = (const float*)d_in[5];
    prm.eWih1 = (const float*)d_in[6];
    prm.eWhh1 = (const float*)d_in[7];
    prm.ebih1 = (const float*)d_in[8];
    prm.ebhh1 = (const float*)d_in[9];
    prm.dWih0 = (const float*)d_in[10];
    prm.dWhh0 = (const float*)d_in[11];
    prm.dbih0 = (const float*)d_in[12];
    prm.dbhh0 = (const float*)d_in[13];
    prm.dWih1 = (const float*)d_in[14];
    prm.dWhh1 = (const float*)d_in[15];
    prm.dbih1 = (const float*)d_in[16];
    prm.dbhh1 = (const float*)d_in[17];
    prm.qW    = (const float*)d_in[18];
    prm.qb    = (const float*)d_in[19];
    prm.outW  = (const float*)d_in[20];
    prm.outb  = (const float*)d_in[21];
    prm.ws    = (float*)d_ws;
    prm.vecO  = (float*)d_out;
    prm.hidO  = prm.vecO + (ll)BB * MLEN * VV;
    prm.attnO = prm.hidO + (ll)2 * BB * HH;

    hipMemsetAsync(d_ws, 0, 16384, stream);  // barrier gen + tree counters
    void* args[] = { &prm };
    if (ws_size >= (size_t)WS_NEED) {
        hipLaunchCooperativeKernel((void*)kmain<1>, dim3(256), dim3(512), args, 0, stream);
    } else {
        hipLaunchCooperativeKernel((void*)kmain<0>, dim3(256), dim3(512), args, 0, stream);
    }
}

// Round 15
// 28097.012 us; speedup vs baseline: 2.2452x; 1.0478x over previous
//
#include <hip/hip_runtime.h>
#include <math.h>

#define BB 128
#define TT 256
#define HH 512
#define VV 32
#define MLEN 128
#define SLOT 65536          // HH*BB floats

// Static LDS layout (floats), 130048 bytes (R2-verified):
#define WT_OFF 0
#define QT_OFF 24576
#define PR_OFF 26624
#define SC_OFF 28416
#define SM_FLOATS 32512

// pair-packed (8B) layouts for agent-scope exchange buffers:
#define HX(d, b) ((((d) >> 1) << 8) + ((b) << 1) + ((d) & 1))
#define SX(t, b) ((((t) >> 1) << 8) + ((b) << 1) + ((t) & 1))
// quad-packed (16B) layout for the big plain-load streams (encO, Pm):
#define QX(d, b) ((((d) >> 2) << 9) + ((b) << 2) + ((d) & 3))

typedef long long ll;

// PM-variant workspace extras (float offsets within f = ws+8192):
#define PM_OFF   17317888LL                    // Pm [256 t][512 d][128 b] quad-packed
#define QWT_OFF  (PM_OFF + 16777216LL)         // qW^T [512 d][512 j]
#define CT_OFF   (QWT_OFF + 262144LL)          // cT [256 t][128 b] pair-packed
#define WS_NEED  ((8192LL + CT_OFF + 32768LL) * 4)   // ~137.6 MB

struct P {
    const float *x, *emb;
    const float *eWih0, *eWhh0, *ebih0, *ebhh0;
    const float *eWih1, *eWhh1, *ebih1, *ebhh1;
    const float *dWih0, *dWhh0, *dbih0, *dbhh0;
    const float *dWih1, *dWhh1, *dbih1, *dbhh1;
    const float *qW, *qb, *outW, *outb;
    float *ws;
    float *vecO, *hidO, *attnO;
};

__device__ __forceinline__ float sigf(float v) { return 1.0f / (1.0f + __expf(-v)); }

__device__ __forceinline__ float ldA(const float* p) {
    return __hip_atomic_load(p, __ATOMIC_RELAXED, __HIP_MEMORY_SCOPE_AGENT);
}
__device__ __forceinline__ float2 ldA2(const float* p) {
    unsigned long long v = __hip_atomic_load((const unsigned long long*)p,
                                             __ATOMIC_RELAXED, __HIP_MEMORY_SCOPE_AGENT);
    union { unsigned long long u; float2 f; } c; c.u = v; return c.f;
}
__device__ __forceinline__ void stA(float* p, float v) {
    __hip_atomic_store(p, v, __ATOMIC_RELAXED, __HIP_MEMORY_SCOPE_AGENT);
}
__device__ __forceinline__ int ldAi(const int* p) {
    return __hip_atomic_load(p, __ATOMIC_RELAXED, __HIP_MEMORY_SCOPE_AGENT);
}
__device__ __forceinline__ void stAi(int* p, int v) {
    __hip_atomic_store(p, v, __ATOMIC_RELAXED, __HIP_MEMORY_SCOPE_AGENT);
}

__device__ __forceinline__ void gbar(int* W, int target) {
    __syncthreads();
    if (threadIdx.x == 0) {
        int par = target & 1;
        int g = blockIdx.x & 15;
        int* gc = W + 32 + (par * 16 + g) * 32;
        if (__hip_atomic_fetch_add(gc, 1, __ATOMIC_RELAXED, __HIP_MEMORY_SCOPE_AGENT) == 15) {
            __hip_atomic_store(gc, 0, __ATOMIC_RELAXED, __HIP_MEMORY_SCOPE_AGENT);
            int* rc = W + 1056 + par * 32;
            if (__hip_atomic_fetch_add(rc, 1, __ATOMIC_RELAXED, __HIP_MEMORY_SCOPE_AGENT) == 15) {
                __hip_atomic_store(rc, 0, __ATOMIC_RELAXED, __HIP_MEMORY_SCOPE_AGENT);
                __hip_atomic_store(W, target, __ATOMIC_RELAXED, __HIP_MEMORY_SCOPE_AGENT);
            }
        }
        while (__hip_atomic_load(W, __ATOMIC_RELAXED, __HIP_MEMORY_SCOPE_AGENT) < target)
            __builtin_amdgcn_s_sleep(2);
    }
    __syncthreads();
}

template<int PM>
__global__ __launch_bounds__(512, 1) void kmain(P p) {
    __shared__ __align__(16) float smu[SM_FLOATS];
    const int tid = threadIdx.x;
    const int lane = tid & 63;
    const int wv = tid >> 6;
    const int blk = blockIdx.x;

    int* W = (int*)p.ws;
    int* tok = W + 4096;
    float* f = (float*)p.ws + 8192;
    float* eh0 = f;
    float* eh1 = f + 2 * SLOT;
    float* inp = f + 4 * SLOT;
    float* qbm = f + 5 * SLOT;
    float* scoresB = f + 6 * SLOT;
    float* T = f + 6 * SLOT + SLOT / 2;
    float* xT = T + 3 * HH * VV;
    float* encO = f + (SLOT / 4) * 33;
    float* Pm  = f + PM_OFF;
    float* qWTp = f + QWT_OFF;
    float* cTp  = f + CT_OFF;

    const float4* t4 = (const float4*)smu;
    const float4* t4q = (const float4*)(smu + QT_OFF);

    const int jg = blk >> 1;
    const int bh = blk & 1;
    const int b2 = bh * 64 + lane;
    int bar = 0;

    // ================= INIT =================
    {
        stA(eh0 + blk * 1024 + tid, 0.0f);
        stA(eh0 + blk * 1024 + 512 + tid, 0.0f);
        if (tid < 256) {
            int idx = blk * 256 + tid;
            int t = idx >> 8, c = (idx >> 7) & 1, b = idx & 127;
            stA(xT + idx, p.x[((ll)b * TT + t) * 2 + c]);
        }
        if (tid < 192) {
            int unit = blk * 192 + tid;
            int v = unit & 31, gj = unit >> 5;
            const float* wrow = p.dWih0 + (ll)gj * 1024;
            const float* erow = p.emb + (ll)v * HH;
            float acc = 0.0f;
#pragma unroll 8
            for (int d = 0; d < HH; ++d) acc = fmaf(wrow[d], erow[d], acc);
            stA(T + unit, acc);
        }
        if constexpr (PM) {
            // qW^T build: qWT[d*512+j] = qW[j*512+d]
#pragma unroll
            for (int r = 0; r < 2; ++r) {
                int k = blk * 1024 + r * 512 + tid;
                int d = k >> 9, j = k & 511;
                stA(qWTp + k, p.qW[(ll)j * HH + d]);
            }
        }
#pragma unroll
        for (int jl = 0; jl < 4; ++jl)
            smu[QT_OFF + jl * 512 + tid] = p.qW[((ll)(jg * 4 + jl)) * HH + tid];
#pragma unroll
        for (int r = 0; r < 24; ++r) {
            int g = r >> 2, jl = r & 3, j = jg * 4 + jl;
            const float* src = (g < 3) ? (p.eWhh0 + (ll)(g * HH + j) * HH)
                                       : (p.eWih1 + (ll)((g - 3) * HH + j) * HH);
            smu[WT_OFF + r * 512 + tid] = src[tid];
        }
#pragma unroll
        for (int r = 0; r < 12; ++r) {
            int g = r >> 2, jl = r & 3, j = jg * 4 + jl;
            smu[WT_OFF + (24 + r) * 512 + tid] = p.eWhh1[(ll)(g * HH + j) * HH + tid];
        }
        gbar(W, ++bar);
    }

    // ================= ENCODER =================
    for (int t = 0; t <= TT; ++t) {
        const float* h0s = eh0 + (((t + 1) & 1) ? SLOT : 0);
        float*       h0d = eh0 + ((t & 1) ? SLOT : 0);
        const float* h1s = eh1 + (((t + 1) & 1) ? SLOT : 0);
        float*       h1d = eh1 + ((t & 1) ? SLOT : 0);

        smu[PR_OFF + tid] = 0.0f;
        smu[PR_OFF + 512 + tid] = 0.0f;
        smu[PR_OFF + 1024 + tid] = 0.0f;
        if (tid < 256) smu[PR_OFF + 1536 + tid] = 0.0f;
        __syncthreads();

        {
            const int rotE = jg & 7;
            const int ds0 = wv * 64;
            float acc[36];
#pragma unroll
            for (int r = 0; r < 36; ++r) acc[r] = 0.0f;
            float av[2][8], bv[2][8];
            {
                const int d0c = ds0 + rotE * 8;
#pragma unroll
                for (int k = 0; k < 4; ++k) {
                    float2 va = ldA2(h0s + HX(d0c + 2 * k, b2));
                    av[0][2 * k] = va.x; av[0][2 * k + 1] = va.y;
                    float2 vb = ldA2(h1s + HX(d0c + 2 * k, b2));
                    bv[0][2 * k] = vb.x; bv[0][2 * k + 1] = vb.y;
                }
            }
#pragma unroll
            for (int c = 0; c < 8; ++c) {
                const int cb = c & 1, pb = cb ^ 1;
                if (c < 7) {
                    const int dn = ds0 + ((c + 1 + rotE) & 7) * 8;
#pragma unroll
                    for (int k = 0; k < 4; ++k) {
                        float2 va = ldA2(h0s + HX(dn + 2 * k, b2));
                        av[pb][2 * k] = va.x; av[pb][2 * k + 1] = va.y;
                        float2 vb = ldA2(h1s + HX(dn + 2 * k, b2));
                        bv[pb][2 * k] = vb.x; bv[pb][2 * k + 1] = vb.y;
                    }
                }
                const int db = ds0 + ((c + rotE) & 7) * 8;
#pragma unroll
                for (int h2 = 0; h2 < 2; ++h2) {
                    const int q4 = (db + h2 * 4) >> 2;
#pragma unroll
                    for (int r = 0; r < 24; ++r) {
                        float4 w = t4[r * 128 + q4];
                        acc[r] = fmaf(w.x, av[cb][h2 * 4 + 0], acc[r]);
                        acc[r] = fmaf(w.y, av[cb][h2 * 4 + 1], acc[r]);
                        acc[r] = fmaf(w.z, av[cb][h2 * 4 + 2], acc[r]);
                        acc[r] = fmaf(w.w, av[cb][h2 * 4 + 3], acc[r]);
                    }
#pragma unroll
                    for (int r = 0; r < 12; ++r) {
                        float4 w = t4[(24 + r) * 128 + q4];
                        acc[24 + r] = fmaf(w.x, bv[cb][h2 * 4 + 0], acc[24 + r]);
                        acc[24 + r] = fmaf(w.y, bv[cb][h2 * 4 + 1], acc[24 + r]);
                        acc[24 + r] = fmaf(w.z, bv[cb][h2 * 4 + 2], acc[24 + r]);
                        acc[24 + r] = fmaf(w.w, bv[cb][h2 * 4 + 3], acc[24 + r]);
                    }
                }
            }
#pragma unroll
            for (int r = 0; r < 24; ++r)
                unsafeAtomicAdd(&smu[PR_OFF + r * 64 + lane], acc[r]);
#pragma unroll
            for (int r = 0; r < 12; ++r) {
                int g = r >> 2;
                int prow = (g < 2) ? (12 + g * 4) : 24;
                unsafeAtomicAdd(&smu[PR_OFF + (prow + (r & 3)) * 64 + lane], acc[24 + r]);
            }
        }
        __syncthreads();

        if (wv < 4) {
            if (t < TT) {
                int jl = wv, j = jg * 4 + jl;
                float* pr = smu + PR_OFF;
                float hr = pr[(0 + jl) * 64 + lane] + p.ebhh0[j];
                float hz = pr[(4 + jl) * 64 + lane] + p.ebhh0[HH + j];
                float hn = pr[(8 + jl) * 64 + lane] + p.ebhh0[2 * HH + j];
                float x0 = xT[t * 256 + b2], x1 = xT[t * 256 + 128 + b2];
                float ir = fmaf(p.eWih0[j * 2], x0, fmaf(p.eWih0[j * 2 + 1], x1, p.ebih0[j]));
                float iz = fmaf(p.eWih0[(HH + j) * 2], x0, fmaf(p.eWih0[(HH + j) * 2 + 1], x1, p.ebih0[HH + j]));
                float in_ = fmaf(p.eWih0[(2 * HH + j) * 2], x0, fmaf(p.eWih0[(2 * HH + j) * 2 + 1], x1, p.ebih0[2 * HH + j]));
                float r = sigf(ir + hr), z = sigf(iz + hz);
                float n = tanhf(in_ + r * hn);
                float hp = ldA(h0s + HX(j, b2));
                stA(h0d + HX(j, b2), (1.0f - z) * n + z * hp);
            }
        } else if (t >= 1) {
            int jl = wv - 4, j = jg * 4 + jl;
            float* pr = smu + PR_OFF;
            float rs = pr[(12 + jl) * 64 + lane] + p.ebih1[j] + p.ebhh1[j];
            float zs = pr[(16 + jl) * 64 + lane] + p.ebih1[HH + j] + p.ebhh1[HH + j];
            float in1 = pr[(20 + jl) * 64 + lane] + p.ebih1[2 * HH + j];
            float hn1 = pr[(24 + jl) * 64 + lane] + p.ebhh1[2 * HH + j];
            float r = sigf(rs), z = sigf(zs);
            float n = tanhf(in1 + r * hn1);
            float hp = ldA(h1s + HX(j, b2));
            float hv = (1.0f - z) * n + z * hp;
            stA(h1d + HX(j, b2), hv);
            stA(encO + (ll)(t - 1) * (HH * BB) + QX(j, b2), hv);
        }
        gbar(W, ++bar);
    }

    // ================= DEC-INIT =================
    {
        if (tid < 256) smu[PR_OFF + tid] = 0.0f;
#pragma unroll
        for (int r = 0; r < 12; ++r) {
            int g = r >> 2, jl = r & 3, j = jg * 4 + jl;
            smu[WT_OFF + r * 1024 + tid]              = p.dWih0[(ll)(g * HH + j) * 1024 + 512 + tid];
            smu[WT_OFF + r * 1024 + 512 + tid]        = p.dWhh0[(ll)(g * HH + j) * HH + tid];
            smu[WT_OFF + (12 + r) * 1024 + tid]       = p.dWih1[(ll)(g * HH + j) * HH + tid];
            smu[WT_OFF + (12 + r) * 1024 + 512 + tid] = p.dWhh1[(ll)(g * HH + j) * HH + tid];
        }
        __syncthreads();
        if constexpr (!PM) {
            const float* h1c = eh1;  // slot 0
            const int ds0 = wv * 64;
            float acc[4] = {0, 0, 0, 0};
            float av[8];
            for (int c = 0; c < 8; ++c) {
                int db = ds0 + c * 8;
#pragma unroll
                for (int k = 0; k < 4; ++k) {
                    float2 v = ldA2(h1c + HX(db + 2 * k, b2));
                    av[2 * k] = v.x; av[2 * k + 1] = v.y;
                }
#pragma unroll
                for (int h2 = 0; h2 < 2; ++h2) {
                    int q4 = (db + h2 * 4) >> 2;
#pragma unroll
                    for (int jl = 0; jl < 4; ++jl) {
                        float4 w = t4q[jl * 128 + q4];
                        acc[jl] = fmaf(w.x, av[h2 * 4 + 0], acc[jl]);
                        acc[jl] = fmaf(w.y, av[h2 * 4 + 1], acc[jl]);
                        acc[jl] = fmaf(w.z, av[h2 * 4 + 2], acc[jl]);
                        acc[jl] = fmaf(w.w, av[h2 * 4 + 3], acc[jl]);
                    }
                }
            }
#pragma unroll
            for (int jl = 0; jl < 4; ++jl)
                unsafeAtomicAdd(&smu[PR_OFF + jl * 64 + lane], acc[jl]);
            __syncthreads();
            if (wv < 4) {
                int j = jg * 4 + wv;
                stA(qbm + HX(j, b2), smu[PR_OFF + wv * 64 + lane] + p.qb[j]);
            }
        } else {
            // Pm[t][d][b] = sum_j qW[j][d]*encO[t][j][b]; cT[t][b] = sum_j qb[j]*encO[t][j][b]
            const int t0p = (blk >> 1) * 2;
#pragma unroll 1
            for (int tt = 0; tt < 2; ++tt) {
                const int t = t0p + tt;
                const float* Eb = encO + (ll)t * (HH * BB) + (b2 << 2);
                float* Pb = Pm + (ll)t * (HH * BB);
#pragma unroll 1
                for (int dc = 0; dc < 8; ++dc) {
                    const int dbase = wv * 64 + dc * 8;
                    float acc8[8];
#pragma unroll
                    for (int u = 0; u < 8; ++u) acc8[u] = 0.0f;
                    const float4* q0 = (const float4*)(qWTp + (ll)(dbase + 0) * HH);
                    const float4* q1 = (const float4*)(qWTp + (ll)(dbase + 1) * HH);
                    const float4* q2p = (const float4*)(qWTp + (ll)(dbase + 2) * HH);
                    const float4* q3 = (const float4*)(qWTp + (ll)(dbase + 3) * HH);
                    const float4* q4p = (const float4*)(qWTp + (ll)(dbase + 4) * HH);
                    const float4* q5 = (const float4*)(qWTp + (ll)(dbase + 5) * HH);
                    const float4* q6 = (const float4*)(qWTp + (ll)(dbase + 6) * HH);
                    const float4* q7 = (const float4*)(qWTp + (ll)(dbase + 7) * HH);
#pragma unroll 4
                    for (int jq = 0; jq < 128; ++jq) {
                        float4 e4 = *(const float4*)(Eb + ((ll)jq << 9));
                        float4 w;
                        w = q0[jq];
                        acc8[0] = fmaf(w.x, e4.x, fmaf(w.y, e4.y, fmaf(w.z, e4.z, fmaf(w.w, e4.w, acc8[0]))));
                        w = q1[jq];
                        acc8[1] = fmaf(w.x, e4.x, fmaf(w.y, e4.y, fmaf(w.z, e4.z, fmaf(w.w, e4.w, acc8[1]))));
                        w = q2p[jq];
                        acc8[2] = fmaf(w.x, e4.x, fmaf(w.y, e4.y, fmaf(w.z, e4.z, fmaf(w.w, e4.w, acc8[2]))));
                        w = q3[jq];
                        acc8[3] = fmaf(w.x, e4.x, fmaf(w.y, e4.y, fmaf(w.z, e4.z, fmaf(w.w, e4.w, acc8[3]))));
                        w = q4p[jq];
                        acc8[4] = fmaf(w.x, e4.x, fmaf(w.y, e4.y, fmaf(w.z, e4.z, fmaf(w.w, e4.w, acc8[4]))));
                        w = q5[jq];
                        acc8[5] = fmaf(w.x, e4.x, fmaf(w.y, e4.y, fmaf(w.z, e4.z, fmaf(w.w, e4.w, acc8[5]))));
                        w = q6[jq];
                        acc8[6] = fmaf(w.x, e4.x, fmaf(w.y, e4.y, fmaf(w.z, e4.z, fmaf(w.w, e4.w, acc8[6]))));
                        w = q7[jq];
                        acc8[7] = fmaf(w.x, e4.x, fmaf(w.y, e4.y, fmaf(w.z, e4.z, fmaf(w.w, e4.w, acc8[7]))));
                    }
#pragma unroll
                    for (int u = 0; u < 8; ++u) {
                        int d = dbase + u;
                        stA(Pb + QX(d, b2), acc8[u]);
                    }
                }
            }
            if (wv == 0) {
#pragma unroll 1
                for (int tt = 0; tt < 2; ++tt) {
                    const int t = t0p + tt;
                    const float* Eb = encO + (ll)t * (HH * BB) + (b2 << 2);
                    float acc = 0.0f;
#pragma unroll 4
                    for (int jq = 0; jq < 128; ++jq) {
                        float4 e4 = *(const float4*)(Eb + ((ll)jq << 9));
                        float4 q4v = *(const float4*)(p.qb + jq * 4);
                        acc = fmaf(q4v.x, e4.x, fmaf(q4v.y, e4.y, fmaf(q4v.z, e4.z, fmaf(q4v.w, e4.w, acc))));
                    }
                    stA(cTp + SX(t, b2), acc);
                }
            }
        }
        if (blk == 128 && tid < BB) stAi(tok + tid, 0);
        gbar(W, ++bar);
    }

    // ================= DECODER =================
    for (int s = 0; s < MLEN; ++s) {
        const float* h0s = eh0 + (((s + 1) & 1) ? SLOT : 0);
        float*       g0d = eh0 + ((s & 1) ? SLOT : 0);
        const float* h1s = eh1 + ((s & 1) ? SLOT : 0);
        float*       h1d = eh1 + (((s + 1) & 1) ? SLOT : 0);

        // --- A1: scores (+ merged logits for PM); quad loads on Pm/encO ---
        {
            const int rotA = jg & 7;
            const int t0 = (blk >> 1) * 2;
            if (tid < 128) smu[PR_OFF + tid] = 0.0f;
            __syncthreads();
            const int js = wv * 64;
            float a0 = 0.0f, a1 = 0.0f;
            float qv[2][8], e0[2][8], e1[2][8];
            const float* S0 = PM ? (Pm + (ll)t0 * (HH * BB)) : (encO + (ll)t0 * (HH * BB));
            const float* S1 = PM ? (Pm + (ll)(t0 + 1) * (HH * BB)) : (encO + (ll)(t0 + 1) * (HH * BB));
            const float* Qs = PM ? h1s : qbm;
            {
                const int j0 = js + rotA * 8;
                const float* eb0 = S0 + ((j0 >> 2) << 9) + (b2 << 2);
                const float* eb1 = S1 + ((j0 >> 2) << 9) + (b2 << 2);
                float4 x0 = *(const float4*)(eb0);
                float4 x1 = *(const float4*)(eb0 + 512);
                float4 y0 = *(const float4*)(eb1);
                float4 y1 = *(const float4*)(eb1 + 512);
                e0[0][0] = x0.x; e0[0][1] = x0.y; e0[0][2] = x0.z; e0[0][3] = x0.w;
                e0[0][4] = x1.x; e0[0][5] = x1.y; e0[0][6] = x1.z; e0[0][7] = x1.w;
                e1[0][0] = y0.x; e1[0][1] = y0.y; e1[0][2] = y0.z; e1[0][3] = y0.w;
                e1[0][4] = y1.x; e1[0][5] = y1.y; e1[0][6] = y1.z; e1[0][7] = y1.w;
#pragma unroll
                for (int k = 0; k < 4; ++k) {
                    float2 q2 = ldA2(Qs + HX(j0 + 2 * k, b2));
                    qv[0][2 * k] = q2.x; qv[0][2 * k + 1] = q2.y;
                }
            }
#pragma unroll
            for (int c = 0; c < 8; ++c) {
                const int cb = c & 1, pb = cb ^ 1;
                if (c < 7) {
                    const int jn = js + ((c + 1 + rotA) & 7) * 8;
                    const float* eb0 = S0 + ((jn >> 2) << 9) + (b2 << 2);
                    const float* eb1 = S1 + ((jn >> 2) << 9) + (b2 << 2);
                    float4 x0 = *(const float4*)(eb0);
                    float4 x1 = *(const float4*)(eb0 + 512);
                    float4 y0 = *(const float4*)(eb1);
                    float4 y1 = *(const float4*)(eb1 + 512);
                    e0[pb][0] = x0.x; e0[pb][1] = x0.y; e0[pb][2] = x0.z; e0[pb][3] = x0.w;
                    e0[pb][4] = x1.x; e0[pb][5] = x1.y; e0[pb][6] = x1.z; e0[pb][7] = x1.w;
                    e1[pb][0] = y0.x; e1[pb][1] = y0.y; e1[pb][2] = y0.z; e1[pb][3] = y0.w;
                    e1[pb][4] = y1.x; e1[pb][5] = y1.y; e1[pb][6] = y1.z; e1[pb][7] = y1.w;
#pragma unroll
                    for (int k = 0; k < 4; ++k) {
                        float2 q2 = ldA2(Qs + HX(jn + 2 * k, b2));
                        qv[pb][2 * k] = q2.x; qv[pb][2 * k + 1] = q2.y;
                    }
                }
#pragma unroll
                for (int u = 0; u < 8; ++u) {
                    a0 = fmaf(qv[cb][u], e0[cb][u], a0);
                    a1 = fmaf(qv[cb][u], e1[cb][u], a1);
                }
            }
            unsafeAtomicAdd(&smu[PR_OFF + lane], a0);
            unsafeAtomicAdd(&smu[PR_OFF + 64 + lane], a1);
            __syncthreads();
            if (wv < 2) {
                float base = smu[PR_OFF + wv * 64 + lane];
                if constexpr (PM) base += cTp[SX(t0 + wv, b2)];
                stA(scoresB + SX(t0 + wv, b2), base);
            }
            if constexpr (PM) {
                if (blk >= 128 && blk < 160 && s >= 1) {
                    __syncthreads();
                    const int bb = (blk - 128) * 4;
#pragma unroll
                    for (int i = 0; i < 4; ++i) {
                        int f2 = i * 512 + tid;
                        int d = f2 >> 2, bi2 = f2 & 3;
                        smu[SC_OFF + f2] = ldA(h1s + HX(d, bb + bi2));
                    }
                    __syncthreads();
                    if (tid < 128) {
                        const int bl = tid >> 5, v = tid & 31;
                        float acc = 0.0f;
                        for (int d4 = 0; d4 < 128; ++d4) {
                            float4 w4 = *(const float4*)(p.outW + (ll)v * HH + d4 * 4);
                            acc = fmaf(w4.x, smu[SC_OFF + (d4 * 4 + 0) * 4 + bl], acc);
                            acc = fmaf(w4.y, smu[SC_OFF + (d4 * 4 + 1) * 4 + bl], acc);
                            acc = fmaf(w4.z, smu[SC_OFF + (d4 * 4 + 2) * 4 + bl], acc);
                            acc = fmaf(w4.w, smu[SC_OFF + (d4 * 4 + 3) * 4 + bl], acc);
                        }
                        acc += p.outb[v];
                        p.vecO[((ll)(bb + bl) * MLEN + (s - 1)) * VV + v] = acc;
                        smu[SC_OFF + 2048 + tid] = acc;
                    }
                    __syncthreads();
                    if (tid < 4) {
                        int base = SC_OFF + 2048 + tid * 32;
                        float best = smu[base];
                        int bi2 = 0;
#pragma unroll
                        for (int u = 1; u < 32; ++u) {
                            float val = smu[base + u];
                            if (val > best) { best = val; bi2 = u; }
                        }
                        stAi(tok + bb + tid, bi2);
                    }
                }
            }
        }
        gbar(W, ++bar);

        // --- A2: softmax + context; quad loads on encO ---
        {
            const int d0 = jg * 4;
            float sv[32];
#pragma unroll
            for (int kp = 0; kp < 16; ++kp) {
                float2 v = ldA2(scoresB + ((wv * 16 + kp) << 8) + (b2 << 1));
                sv[2 * kp] = v.x; sv[2 * kp + 1] = v.y;
            }
            if (tid < 256) smu[PR_OFF + tid] = 0.0f;
            float mp = sv[0];
#pragma unroll
            for (int k = 1; k < 32; ++k) mp = fmaxf(mp, sv[k]);
            smu[SC_OFF + wv * 64 + lane] = mp;
            __syncthreads();
            float m = smu[SC_OFF + lane];
#pragma unroll
            for (int u = 1; u < 8; ++u) m = fmaxf(m, smu[SC_OFF + u * 64 + lane]);
            float e[32], lp = 0.0f;
#pragma unroll
            for (int k = 0; k < 32; ++k) { e[k] = __expf(sv[k] - m); lp += e[k]; }
            smu[SC_OFF + 512 + wv * 64 + lane] = lp;
            __syncthreads();
            float l = smu[SC_OFF + 512 + lane];
#pragma unroll
            for (int u = 1; u < 8; ++u) l += smu[SC_OFF + 512 + u * 64 + lane];
            float rl = 1.0f / l;
            if (blk < 16 && wv == jg) {
#pragma unroll
                for (int k = 0; k < 32; ++k) smu[SC_OFF + 1024 + k * 65 + lane] = e[k] * rl;
            }
            // context: one float4 per (t) covering d0..d0+3
            float c4[4] = {0, 0, 0, 0};
            float ev[2][32];
            const ll dqoff = ((ll)(d0 >> 2) << 9) + (b2 << 2);
#pragma unroll
            for (int u = 0; u < 8; ++u) {
                float4 q = *(const float4*)(encO + (ll)(wv * 32 + u) * (HH * BB) + dqoff);
                ev[0][u * 4 + 0] = q.x; ev[0][u * 4 + 1] = q.y;
                ev[0][u * 4 + 2] = q.z; ev[0][u * 4 + 3] = q.w;
            }
#pragma unroll
            for (int kb = 0; kb < 4; ++kb) {
                const int cb = kb & 1, pb = cb ^ 1;
                if (kb < 3) {
#pragma unroll
                    for (int u = 0; u < 8; ++u) {
                        float4 q = *(const float4*)(encO + (ll)(wv * 32 + (kb + 1) * 8 + u) * (HH * BB) + dqoff);
                        ev[pb][u * 4 + 0] = q.x; ev[pb][u * 4 + 1] = q.y;
                        ev[pb][u * 4 + 2] = q.z; ev[pb][u * 4 + 3] = q.w;
                    }
                }
#pragma unroll
                for (int u = 0; u < 8; ++u) {
                    const int k = kb * 8 + u;
                    c4[0] = fmaf(e[k], ev[cb][u * 4 + 0], c4[0]);
                    c4[1] = fmaf(e[k], ev[cb][u * 4 + 1], c4[1]);
                    c4[2] = fmaf(e[k], ev[cb][u * 4 + 2], c4[2]);
                    c4[3] = fmaf(e[k], ev[cb][u * 4 + 3], c4[3]);
                }
            }
#pragma unroll
            for (int kk = 0; kk < 4; ++kk)
                unsafeAtomicAdd(&smu[PR_OFF + kk * 64 + lane], c4[kk]);
            __syncthreads();
            if (tid < 256) {
                int kk = tid >> 6, ln = tid & 63;
                float l2 = smu[SC_OFF + 512 + ln];
#pragma unroll
                for (int u = 1; u < 8; ++u) l2 += smu[SC_OFF + 512 + u * 64 + ln];
                float val = smu[PR_OFF + kk * 64 + ln] / l2;
                stA(inp + HX(d0 + kk, bh * 64 + ln), val);
            }
            if (blk < 16) {
                int bi = tid >> 3, tj = tid & 7;
#pragma unroll
                for (int u = 0; u < 4; ++u) {
                    int tl = tj * 4 + u;
                    p.attnO[((ll)(bh * 64 + bi) * MLEN + s) * TT + jg * 32 + tl] = smu[SC_OFF + 1024 + tl * 65 + bi];
                }
            }
        }
        gbar(W, ++bar);

        // --- G0 ---
        {
            const int rotG = jg & 15;
            smu[PR_OFF + tid] = 0.0f;
            smu[PR_OFF + 512 + tid] = 0.0f;
            __syncthreads();
            const int ctxw = (wv < 4);
            const float* stream = ctxw ? inp : h0s;
            const int ds0 = (wv & 3) * 128;
            const int tb = ctxw ? 0 : 512;
            float acc[12];
#pragma unroll
            for (int r = 0; r < 12; ++r) acc[r] = 0.0f;
            float av[2][8];
            {
                const int d0c = ds0 + rotG * 8;
#pragma unroll
                for (int k = 0; k < 4; ++k) {
                    float2 v = ldA2(stream + HX(d0c + 2 * k, b2));
                    av[0][2 * k] = v.x; av[0][2 * k + 1] = v.y;
                }
            }
#pragma unroll
            for (int c = 0; c < 16; ++c) {
                const int cb = c & 1, pb = cb ^ 1;
                if (c < 15) {
                    const int dn = ds0 + ((c + 1 + rotG) & 15) * 8;
#pragma unroll
                    for (int k = 0; k < 4; ++k) {
                        float2 v = ldA2(stream + HX(dn + 2 * k, b2));
                        av[pb][2 * k] = v.x; av[pb][2 * k + 1] = v.y;
                    }
                }
                const int db = ds0 + ((c + rotG) & 15) * 8;
#pragma unroll
                for (int h2 = 0; h2 < 2; ++h2) {
                    const int q4 = (tb + db + h2 * 4) >> 2;
#pragma unroll
                    for (int r = 0; r < 12; ++r) {
                        float4 w = t4[r * 256 + q4];
                        acc[r] = fmaf(w.x, av[cb][h2 * 4 + 0], acc[r]);
                        acc[r] = fmaf(w.y, av[cb][h2 * 4 + 1], acc[r]);
                        acc[r] = fmaf(w.z, av[cb][h2 * 4 + 2], acc[r]);
                        acc[r] = fmaf(w.w, av[cb][h2 * 4 + 3], acc[r]);
                    }
                }
            }
#pragma unroll
            for (int r = 0; r < 12; ++r) {
                int g = r >> 2;
                int prow = (g < 2) ? g * 4 : (ctxw ? 8 : 12);
                unsafeAtomicAdd(&smu[PR_OFF + (prow + (r & 3)) * 64 + lane], acc[r]);
            }
            __syncthreads();
            if (wv < 4) {
                int jl = wv, j = jg * 4 + jl;
                float* pr = smu + PR_OFF;
                int tokb = ldAi(tok + b2);
                float rs = T[(ll)j * 32 + tokb] + pr[(0 + jl) * 64 + lane] + p.dbih0[j] + p.dbhh0[j];
                float zs = T[(ll)(HH + j) * 32 + tokb] + pr[(4 + jl) * 64 + lane] + p.dbih0[HH + j] + p.dbhh0[HH + j];
                float ins = T[(ll)(2 * HH + j) * 32 + tokb] + pr[(8 + jl) * 64 + lane] + p.dbih0[2 * HH + j];
                float hns = pr[(12 + jl) * 64 + lane] + p.dbhh0[2 * HH + j];
                float r = sigf(rs), z = sigf(zs);
                float n = tanhf(ins + r * hns);
                float hp = ldA(h0s + HX(j, b2));
                stA(g0d + HX(j, b2), (1.0f - z) * n + z * hp);
            }
        }
        gbar(W, ++bar);

        // --- G1 ---
        {
            const int rotG = jg & 15;
            smu[PR_OFF + tid] = 0.0f;
            smu[PR_OFF + 512 + tid] = 0.0f;
            __syncthreads();
            const int iw = (wv < 4);
            const float* stream = iw ? g0d : h1s;
            const int ds0 = (wv & 3) * 128;
            const int tb = iw ? 0 : 512;
            float acc[12];
#pragma unroll
            for (int r = 0; r < 12; ++r) acc[r] = 0.0f;
            float av[2][8];
            {
                const int d0c = ds0 + rotG * 8;
#pragma unroll
                for (int k = 0; k < 4; ++k) {
                    float2 v = ldA2(stream + HX(d0c + 2 * k, b2));
                    av[0][2 * k] = v.x; av[0][2 * k + 1] = v.y;
                }
            }
#pragma unroll
            for (int c = 0; c < 16; ++c) {
                const int cb = c & 1, pb = cb ^ 1;
                if (c < 15) {
                    const int dn = ds0 + ((c + 1 + rotG) & 15) * 8;
#pragma unroll
                    for (int k = 0; k < 4; ++k) {
                        float2 v = ldA2(stream + HX(dn + 2 * k, b2));
                        av[pb][2 * k] = v.x; av[pb][2 * k + 1] = v.y;
                    }
                }
                const int db = ds0 + ((c + rotG) & 15) * 8;
#pragma unroll
                for (int h2 = 0; h2 < 2; ++h2) {
                    const int q4 = (tb + db + h2 * 4) >> 2;
#pragma unroll
                    for (int r = 0; r < 12; ++r) {
                        float4 w = t4[(12 + r) * 256 + q4];
                        acc[r] = fmaf(w.x, av[cb][h2 * 4 + 0], acc[r]);
                        acc[r] = fmaf(w.y, av[cb][h2 * 4 + 1], acc[r]);
                        acc[r] = fmaf(w.z, av[cb][h2 * 4 + 2], acc[r]);
                        acc[r] = fmaf(w.w, av[cb][h2 * 4 + 3], acc[r]);
                    }
                }
            }
#pragma unroll
            for (int r = 0; r < 12; ++r) {
                int g = r >> 2;
                int prow = (g < 2) ? g * 4 : (iw ? 8 : 12);
                unsafeAtomicAdd(&smu[PR_OFF + (prow + (r & 3)) * 64 + lane], acc[r]);
            }
            __syncthreads();
            if (wv < 4) {
                int jl = wv, j = jg * 4 + jl;
                float* pr = smu + PR_OFF;
                float rs = pr[(0 + jl) * 64 + lane] + p.dbih1[j] + p.dbhh1[j];
                float zs = pr[(4 + jl) * 64 + lane] + p.dbih1[HH + j] + p.dbhh1[HH + j];
                float ins = pr[(8 + jl) * 64 + lane] + p.dbih1[2 * HH + j];
                float hns = pr[(12 + jl) * 64 + lane] + p.dbhh1[2 * HH + j];
                float r = sigf(rs), z = sigf(zs);
                float n = tanhf(ins + r * hns);
                float hp = ldA(h1s + HX(j, b2));
                stA(h1d + HX(j, b2), (1.0f - z) * n + z * hp);
            }
        }
        gbar(W, ++bar);

        // --- D (PM=0 only): query + logits/argmax ---
        if constexpr (!PM) {
            const int rotD = jg & 7;
            const float* h1c = h1d;
            if (tid < 256) smu[PR_OFF + tid] = 0.0f;
            __syncthreads();
            {
                const int ds0 = wv * 64;
                float acc4[4] = {0, 0, 0, 0};
                float av[2][8];
                {
                    const int d0c = ds0 + rotD * 8;
#pragma unroll
                    for (int k = 0; k < 4; ++k) {
                        float2 v = ldA2(h1c + HX(d0c + 2 * k, b2));
                        av[0][2 * k] = v.x; av[0][2 * k + 1] = v.y;
                    }
                }
#pragma unroll
                for (int c = 0; c < 8; ++c) {
                    const int cb = c & 1, pb = cb ^ 1;
                    if (c < 7) {
                        const int dn = ds0 + ((c + 1 + rotD) & 7) * 8;
#pragma unroll
                        for (int k = 0; k < 4; ++k) {
                            float2 v = ldA2(h1c + HX(dn + 2 * k, b2));
                            av[pb][2 * k] = v.x; av[pb][2 * k + 1] = v.y;
                        }
                    }
                    const int db = ds0 + ((c + rotD) & 7) * 8;
#pragma unroll
                    for (int h2 = 0; h2 < 2; ++h2) {
                        const int q4 = (db + h2 * 4) >> 2;
#pragma unroll
                        for (int jl = 0; jl < 4; ++jl) {
                            float4 w = t4q[jl * 128 + q4];
                            acc4[jl] = fmaf(w.x, av[cb][h2 * 4 + 0], acc4[jl]);
                            acc4[jl] = fmaf(w.y, av[cb][h2 * 4 + 1], acc4[jl]);
                            acc4[jl] = fmaf(w.z, av[cb][h2 * 4 + 2], acc4[jl]);
                            acc4[jl] = fmaf(w.w, av[cb][h2 * 4 + 3], acc4[jl]);
                        }
                    }
                }
#pragma unroll
                for (int jl = 0; jl < 4; ++jl)
                    unsafeAtomicAdd(&smu[PR_OFF + jl * 64 + lane], acc4[jl]);
            }
            __syncthreads();
            if (wv < 4) {
                int j = jg * 4 + wv;
                stA(qbm + HX(j, b2), smu[PR_OFF + wv * 64 + lane] + p.qb[j]);
            }
            if (blk >= 128 && blk < 160) {
                __syncthreads();
                const int bb = (blk - 128) * 4;
#pragma unroll
                for (int i = 0; i < 4; ++i) {
                    int f2 = i * 512 + tid;
                    int d = f2 >> 2, bi2 = f2 & 3;
                    smu[SC_OFF + f2] = ldA(h1c + HX(d, bb + bi2));
                }
                __syncthreads();
                if (tid < 128) {
                    const int bl = tid >> 5, v = tid & 31;
                    float acc = 0.0f;
                    for (int d4 = 0; d4 < 128; ++d4) {
                        float4 w4 = *(const float4*)(p.outW + (ll)v * HH + d4 * 4);
                        acc = fmaf(w4.x, smu[SC_OFF + (d4 * 4 + 0) * 4 + bl], acc);
                        acc = fmaf(w4.y, smu[SC_OFF + (d4 * 4 + 1) * 4 + bl], acc);
                        acc = fmaf(w4.z, smu[SC_OFF + (d4 * 4 + 2) * 4 + bl], acc);
                        acc = fmaf(w4.w, smu[SC_OFF + (d4 * 4 + 3) * 4 + bl], acc);
                    }
                    acc += p.outb[v];
                    p.vecO[((ll)(bb + bl) * MLEN + s) * VV + v] = acc;
                    smu[SC_OFF + 2048 + tid] = acc;
                }
                __syncthreads();
                if (tid < 4) {
                    int base = SC_OFF + 2048 + tid * 32;
                    float best = smu[base];
                    int bi2 = 0;
#pragma unroll
                    for (int u = 1; u < 32; ++u) {
                        float val = smu[base + u];
                        if (val > best) { best = val; bi2 = u; }
                    }
                    stAi(tok + bb + tid, bi2);
                }
            }
            gbar(W, ++bar);
        }
    }

    // ================= PM epilogue: logits for s = 127 =================
    if constexpr (PM) {
        if (blk >= 128 && blk < 160) {
            const float* h1c = eh1;   // slot 0 = h1 after step 127
            const int bb = (blk - 128) * 4;
            __syncthreads();
#pragma unroll
            for (int i = 0; i < 4; ++i) {
                int f2 = i * 512 + tid;
                int d = f2 >> 2, bi2 = f2 & 3;
                smu[SC_OFF + f2] = ldA(h1c + HX(d, bb + bi2));
            }
            __syncthreads();
            if (tid < 128) {
                const int bl = tid >> 5, v = tid & 31;
                float acc = 0.0f;
                for (int d4 = 0; d4 < 128; ++d4) {
                    float4 w4 = *(const float4*)(p.outW + (ll)v * HH + d4 * 4);
                    acc = fmaf(w4.x, smu[SC_OFF + (d4 * 4 + 0) * 4 + bl], acc);
                    acc = fmaf(w4.y, smu[SC_OFF + (d4 * 4 + 1) * 4 + bl], acc);
                    acc = fmaf(w4.z, smu[SC_OFF + (d4 * 4 + 2) * 4 + bl], acc);
                    acc = fmaf(w4.w, smu[SC_OFF + (d4 * 4 + 3) * 4 + bl], acc);
                }
                acc += p.outb[v];
                p.vecO[((ll)(bb + bl) * MLEN + (MLEN - 1)) * VV + v] = acc;
            }
        }
    }

    // ================= final hidden [2][128][512] =================
    {
        int idx = blk * 512 + tid;
        int l = idx >> 16, rr = idx & 65535;
        int b = rr >> 9, h = rr & 511;
        const float* src = l ? eh1 : (eh0 + SLOT);
        p.hidO[idx] = ldA(src + HX(h, b));
    }
}

extern "C" void kernel_launch(void* const* d_in, const int* in_sizes, int n_in,
                              void* d_out, int out_size, void* d_ws, size_t ws_size,
                              hipStream_t stream) {
    (void)in_sizes; (void)n_in; (void)out_size;
    P prm;
    prm.x     = (const float*)d_in[0];
    prm.emb   = (const float*)d_in[1];
    prm.eWih0 = (const float*)d_in[2];
    prm.eWhh0 = (const float*)d_in[3];
    prm.ebih0 = (const float*)d_in[4];
    prm.ebhh0 = (const float*)d_in[5];
    prm.eWih1 = (const float*)d_in[6];
    prm.eWhh1 = (const float*)d_in[7];
    prm.ebih1 = (const float*)d_in[8];
    prm.ebhh1 = (const float*)d_in[9];
    prm.dWih0 = (const float*)d_in[10];
    prm.dWhh0 = (const float*)d_in[11];
    prm.dbih0 = (const float*)d_in[12];
    prm.dbhh0 = (const float*)d_in[13];
    prm.dWih1 = (const float*)d_in[14];
    prm.dWhh1 = (const float*)d_in[15];
    prm.dbih1 = (const float*)d_in[16];
    prm.dbhh1 = (const float*)d_in[17];
    prm.qW    = (const float*)d_in[18];
    prm.qb    = (const float*)d_in[19];
    prm.outW  = (const float*)d_in[20];
    prm.outb  = (const float*)d_in[21];
    prm.ws    = (float*)d_ws;
    prm.vecO  = (float*)d_out;
    prm.hidO  = prm.vecO + (ll)BB * MLEN * VV;
    prm.attnO = prm.hidO + (ll)2 * BB * HH;

    hipMemsetAsync(d_ws, 0, 16384, stream);  // barrier gen + tree counters
    void* args[] = { &prm };
    if (ws_size >= (size_t)WS_NEED) {
        hipLaunchCooperativeKernel((void*)kmain<1>, dim3(256), dim3(512), args, 0, stream);
    } else {
        hipLaunchCooperativeKernel((void*)kmain<0>, dim3(256), dim3(512), args, 0, stream);
    }
}